// Round 6
// baseline (361.134 us; speedup 1.0000x reference)
//
#include <hip/hip_runtime.h>
#include <hip/hip_bf16.h>
#include <stdint.h>

// ---------------------------------------------------------------------------
// DifferentialBiomedCLIP: x(128,197,768) f32 -> QKV proj -> 12-head attn with
// differential combine -> output proj. bf16 MFMA (16x16x32), f32 accum.
// GEMM: proven 128x128-tile structure (607 TF measured, round 1).
// Attn: NO K-staging (global reads, L1-resident); V transposed in LDS;
//       LDS 33.8 KB -> 4 blocks/CU (was 2). __launch_bounds__(256,4).
// Combine folded into Wp' = [Wp1, Wp2 - lv*Wp1] at weight-cvt time.
// ---------------------------------------------------------------------------

typedef __attribute__((ext_vector_type(4))) float f32x4;
typedef __attribute__((ext_vector_type(8))) short s16x8;
typedef __attribute__((ext_vector_type(8))) __bf16 bf16x8;

typedef const __attribute__((address_space(1))) void* gptr_t;
typedef __attribute__((address_space(3))) void* lptr_t;

__device__ __forceinline__ f32x4 mfma16(s16x8 a, s16x8 b, f32x4 c) {
  return __builtin_amdgcn_mfma_f32_16x16x32_bf16(
      __builtin_bit_cast(bf16x8, a), __builtin_bit_cast(bf16x8, b), c, 0, 0, 0);
}

__device__ __forceinline__ short f2bf(float f) {  // RNE f32->bf16 bits
  unsigned u = __float_as_uint(f);
  u += 0x7fffu + ((u >> 16) & 1u);
  return (short)(u >> 16);
}
__device__ __forceinline__ float bf2f(short s) {
  return __uint_as_float(((unsigned)(unsigned short)s) << 16);
}

__device__ __forceinline__ void gload_lds16(const void* g, void* l) {
  // async global->LDS, 16B per lane; LDS dest = wave-uniform base + lane*16
  __builtin_amdgcn_global_load_lds((gptr_t)g, (lptr_t)l, 16, 0, 0);
}

// ---------------------------------------------------------------------------
__global__ void cvt_f32_to_bf16(const float* __restrict__ src,
                                short* __restrict__ dst, long n8) {
  long i = (long)blockIdx.x * blockDim.x + threadIdx.x;
  const long stride = (long)gridDim.x * blockDim.x;
  for (; i < n8; i += stride) {
    const float4 a = ((const float4*)src)[2 * i];
    const float4 b = ((const float4*)src)[2 * i + 1];
    s16x8 o;
    o[0] = f2bf(a.x); o[1] = f2bf(a.y); o[2] = f2bf(a.z); o[3] = f2bf(a.w);
    o[4] = f2bf(b.x); o[5] = f2bf(b.y); o[6] = f2bf(b.z); o[7] = f2bf(b.w);
    ((s16x8*)dst)[i] = o;
  }
}

// lv = mean_h(exp(min(lq1.lk1,5)) - exp(min(lq2.lk2,5))) + lambda_init
__global__ void lv_kernel(const float* __restrict__ lq1, const float* __restrict__ lk1,
                          const float* __restrict__ lq2, const float* __restrict__ lk2,
                          const float* __restrict__ lambda_init, float* __restrict__ out) {
  const int l = threadIdx.x;
  float v = 0.f;
  if (l < 6) {
    float d1 = 0.f, d2 = 0.f;
    for (int j = 0; j < 64; ++j) {
      d1 += lq1[l * 64 + j] * lk1[l * 64 + j];
      d2 += lq2[l * 64 + j] * lk2[l * 64 + j];
    }
    v = expf(fminf(d1, 5.f)) - expf(fminf(d2, 5.f));
  }
  v += __shfl_xor(v, 1, 64);
  v += __shfl_xor(v, 2, 64);
  v += __shfl_xor(v, 4, 64);
  if (l == 0) out[0] = v * (1.f / 6.f) + lambda_init[0];
}

// Wp' (bf16): cols [0,384) = Wp, cols [384,768) = Wp[:,384:] - lv*Wp[:,:384].
__global__ void cvt_wp_prime(const float* __restrict__ Wp,
                             const float* __restrict__ lvp,
                             short* __restrict__ dst) {
  const int idx = blockIdx.x * blockDim.x + threadIdx.x;  // 73728 chunks of 8
  if (idx >= 73728) return;
  const float lv = *lvp;
  const int ic = idx % 96;  // col-chunk within a row (96 x 8 = 768)
  const float4 a = ((const float4*)Wp)[2 * idx];
  const float4 b = ((const float4*)Wp)[2 * idx + 1];
  float v[8] = {a.x, a.y, a.z, a.w, b.x, b.y, b.z, b.w};
  if (ic >= 48) {  // high half: subtract lv * (same row, col-384)
    const float4 a2 = ((const float4*)Wp)[2 * idx - 96];
    const float4 b2 = ((const float4*)Wp)[2 * idx - 95];
    v[0] -= lv * a2.x; v[1] -= lv * a2.y; v[2] -= lv * a2.z; v[3] -= lv * a2.w;
    v[4] -= lv * b2.x; v[5] -= lv * b2.y; v[6] -= lv * b2.z; v[7] -= lv * b2.w;
  }
  s16x8 o;
#pragma unroll
  for (int j = 0; j < 8; ++j) o[j] = f2bf(v[j]);
  ((s16x8*)dst)[idx] = o;
}

// ---------------------------------------------------------------------------
// C[M,N] = A[M,K] * B[N,K]^T + bias ; A row stride = lda (elements), B packed.
// 128x128 tile, BK=64, 4 waves, 16x16x32 bf16 MFMA, global_load_lds staging,
// XOR chunk swizzle (pre-swizzled global source + swizzled LDS read).
template <int OUT_BF16>
__global__ __launch_bounds__(256) void gemm_bt(const short* __restrict__ A, int lda,
                                               const short* __restrict__ B,
                                               const float* __restrict__ bias,
                                               void* __restrict__ C,
                                               int M, int N, int K) {
  const int nbx = N >> 7;
  const int bx = blockIdx.x % nbx;
  const int by = blockIdx.x / nbx;
  const long m0 = (long)by << 7;
  const int n0 = bx << 7;
  __shared__ short Asm[128 * 64];
  __shared__ short Bsm[128 * 64];
  const int tid = threadIdx.x;
  const int lane = tid & 63;
  const int w = tid >> 6;
  const int wr = w >> 1, wc = w & 1;
  const int r16 = lane & 15, g = lane >> 4;
  f32x4 acc[4][4];
#pragma unroll
  for (int i = 0; i < 4; ++i)
#pragma unroll
    for (int j = 0; j < 4; ++j) acc[i][j] = f32x4{0.f, 0.f, 0.f, 0.f};

  const int nkt = K >> 6;
  for (int kt = 0; kt < nkt; ++kt) {
    __syncthreads();  // all waves done reading LDS from previous step
#pragma unroll
    for (int i = 0; i < 4; ++i) {
      const int c = i * 256 + tid;      // linear 16B chunk id (1024 per tile)
      const int row = c >> 3;           // 8 chunks per 64-elem row
      const int lc = (c & 7) ^ (row & 7);  // logical col-chunk for this slot
      gload_lds16(A + (m0 + row) * lda + (long)kt * 64 + lc * 8,
                  Asm + i * 2048 + w * 512);
      gload_lds16(B + (long)(n0 + row) * K + (long)kt * 64 + lc * 8,
                  Bsm + i * 2048 + w * 512);
    }
    asm volatile("s_waitcnt vmcnt(0)" ::: "memory");
    __syncthreads();
#pragma unroll
    for (int kk = 0; kk < 2; ++kk) {
      s16x8 av[4], bvv[4];
#pragma unroll
      for (int f = 0; f < 4; ++f) {
        const int ar = wr * 64 + f * 16 + r16;
        av[f] = *(const s16x8*)(Asm + ar * 64 + ((((kk << 2) + g) ^ (ar & 7)) << 3));
        const int br = wc * 64 + f * 16 + r16;
        bvv[f] = *(const s16x8*)(Bsm + br * 64 + ((((kk << 2) + g) ^ (br & 7)) << 3));
      }
#pragma unroll
      for (int fm = 0; fm < 4; ++fm)
#pragma unroll
        for (int fn = 0; fn < 4; ++fn)
          acc[fm][fn] = mfma16(av[fm], bvv[fn], acc[fm][fn]);
    }
  }
  // epilogue: D col=lane&15, row=(lane>>4)*4+reg
#pragma unroll
  for (int fm = 0; fm < 4; ++fm)
#pragma unroll
    for (int fn = 0; fn < 4; ++fn) {
      const int col = n0 + wc * 64 + fn * 16 + r16;
      const float bb = bias[col];
#pragma unroll
      for (int r = 0; r < 4; ++r) {
        const long row = m0 + wr * 64 + fm * 16 + g * 4 + r;
        const float v = acc[fm][fn][r] + bb;
        if (OUT_BF16) ((short*)C)[row * (long)N + col] = f2bf(v);
        else          ((float*)C)[row * (long)N + col] = v;
      }
    }
}

// ---------------------------------------------------------------------------
// Attention: one block per (b,h). QKV (25216 x 2304) bf16: cols [0,768)=Q,
// [768,1536)=K, [1536,2304)=V, head-major (h*64+d). Writes O in place over
// the Q columns (each wave reads its own Q rows before writing them).
// K is NOT staged: fragments read directly from global (K/head = 25 KB,
// L1-resident, reused 13 kt x 3-4 q-tiles per wave). V staged transposed in
// LDS (PV needs [d][key] layout). LDS = 29.7K + 4K -> 4 blocks/CU.
__global__ __launch_bounds__(256, 4) void attn_kernel(short* QKV) {
  const int b = blockIdx.x / 12;
  const int h = blockIdx.x % 12;
  __shared__ short Vsm[64 * 232];   // V transposed [d][key], stride 232 elems
  __shared__ short Psm[4][512];     // per-wave 16x32 bf16 P bounce (swizzled)
  const int tid = threadIdx.x;
  const long base = (long)b * 197 * 2304;

  for (int c = tid; c < 224 * 8; c += 256) {  // stage V transposed (zero pad)
    const int key = c % 224, dch = c / 224;
    s16x8 val = {};
    if (key < 197)
      val = *(const s16x8*)(QKV + base + (long)key * 2304 + 1536 + h * 64 + dch * 8);
#pragma unroll
    for (int j = 0; j < 8; ++j) Vsm[(dch * 8 + j) * 232 + key] = val[j];
  }
  __syncthreads();

  const int lane = tid & 63, w = tid >> 6;
  const int r16 = lane & 15, g = lane >> 4;
  short* psw = Psm[w];
  // per-lane K fragment base: row r16 (clamped per kt), col h*64 + g*8
  const short* kbase = QKV + base + 768 + h * 64 + g * 8;

  for (int qt = w; qt < 13; qt += 4) {  // 13 q-tiles of 16 rows, round-robin
    const int q0 = qt * 16;
    int qr = q0 + r16;
    if (qr > 196) qr = 196;  // clamp; clamped rows computed but never stored
    const s16x8 qf0 = *(const s16x8*)(QKV + base + (long)qr * 2304 + h * 64 + g * 8);
    const s16x8 qf1 = *(const s16x8*)(QKV + base + (long)qr * 2304 + h * 64 + 32 + g * 8);

    f32x4 s[13];
#pragma unroll
    for (int kt = 0; kt < 13; ++kt) s[kt] = f32x4{0.f, 0.f, 0.f, 0.f};
#pragma unroll
    for (int kt = 0; kt < 13; ++kt) {
      int krow = kt * 16 + r16;
      if (krow > 196) krow = 196;  // stay in-buffer; masked below anyway
      const s16x8 kf0 = *(const s16x8*)(kbase + (long)krow * 2304);
      const s16x8 kf1 = *(const s16x8*)(kbase + (long)krow * 2304 + 32);
      s[kt] = mfma16(qf0, kf0, s[kt]);
      s[kt] = mfma16(qf1, kf1, s[kt]);
    }
    // scale, mask pad keys, row max (rows at (lane>>4)*4+reg, key=lane&15)
    float mr[4] = {-1e30f, -1e30f, -1e30f, -1e30f};
#pragma unroll
    for (int kt = 0; kt < 13; ++kt)
#pragma unroll
      for (int r = 0; r < 4; ++r) {
        float sv = s[kt][r] * 0.125f;
        if (kt == 12 && r16 >= 5) sv = -1e30f;  // keys 197..207
        s[kt][r] = sv;
        mr[r] = fmaxf(mr[r], sv);
      }
#pragma unroll
    for (int r = 0; r < 4; ++r) {
      mr[r] = fmaxf(mr[r], __shfl_xor(mr[r], 1, 64));
      mr[r] = fmaxf(mr[r], __shfl_xor(mr[r], 2, 64));
      mr[r] = fmaxf(mr[r], __shfl_xor(mr[r], 4, 64));
      mr[r] = fmaxf(mr[r], __shfl_xor(mr[r], 8, 64));
    }
    float sum[4] = {0.f, 0.f, 0.f, 0.f};
#pragma unroll
    for (int kt = 0; kt < 13; ++kt)
#pragma unroll
      for (int r = 0; r < 4; ++r) {
        const float p = __expf(s[kt][r] - mr[r]);
        s[kt][r] = p;
        sum[r] += p;
      }
#pragma unroll
    for (int r = 0; r < 4; ++r) {
      sum[r] += __shfl_xor(sum[r], 1, 64);
      sum[r] += __shfl_xor(sum[r], 2, 64);
      sum[r] += __shfl_xor(sum[r], 4, 64);
      sum[r] += __shfl_xor(sum[r], 8, 64);
    }
    // PV: bounce P through per-wave swizzled LDS tile into MFMA-A layout
    f32x4 o[4];
#pragma unroll
    for (int df = 0; df < 4; ++df) o[df] = f32x4{0.f, 0.f, 0.f, 0.f};
#pragma unroll
    for (int kb = 0; kb < 7; ++kb) {  // 7 blocks of 32 keys (last half-padded)
#pragma unroll
      for (int r = 0; r < 4; ++r) {
        const int prow = g * 4 + r;
        const int sw = (prow & 7) << 4;
        const float p1f = (kb < 6) ? s[(2 * kb + 1) % 13][r] : 0.f;
        *(short*)((char*)psw + ((prow * 64 + r16 * 2) ^ sw)) = f2bf(s[2 * kb][r]);
        *(short*)((char*)psw + ((prow * 64 + (r16 + 16) * 2) ^ sw)) = f2bf(p1f);
      }
      asm volatile("s_waitcnt lgkmcnt(0)" ::: "memory");
      const s16x8 pa =
          *(const s16x8*)((const char*)psw + ((r16 * 64 + g * 16) ^ ((r16 & 7) << 4)));
#pragma unroll
      for (int df = 0; df < 4; ++df) {
        const s16x8 vf = *(const s16x8*)(Vsm + (df * 16 + r16) * 232 + kb * 32 + g * 8);
        o[df] = mfma16(pa, vf, o[df]);
      }
    }
    float rinv[4];
#pragma unroll
    for (int r = 0; r < 4; ++r) rinv[r] = 1.f / sum[r];
#pragma unroll
    for (int df = 0; df < 4; ++df)
#pragma unroll
      for (int r = 0; r < 4; ++r) {
        const int qrow = q0 + g * 4 + r;
        if (qrow < 197)
          QKV[base + (long)qrow * 2304 + h * 64 + df * 16 + r16] =
              f2bf(o[df][r] * rinv[r]);
      }
  }
}

// ---------------------------------------------------------------------------
extern "C" void kernel_launch(void* const* d_in, const int* in_sizes, int n_in,
                              void* d_out, int out_size, void* d_ws, size_t ws_size,
                              hipStream_t stream) {
  (void)in_sizes; (void)n_in; (void)out_size; (void)ws_size;
  const float* x   = (const float*)d_in[0];
  const float* Wq  = (const float*)d_in[1];
  const float* bq  = (const float*)d_in[2];
  const float* Wk  = (const float*)d_in[3];
  const float* bk  = (const float*)d_in[4];
  const float* Wv  = (const float*)d_in[5];
  const float* bv  = (const float*)d_in[6];
  const float* Wp  = (const float*)d_in[7];
  const float* bp  = (const float*)d_in[8];
  const float* lq1 = (const float*)d_in[9];
  const float* lk1 = (const float*)d_in[10];
  const float* lq2 = (const float*)d_in[11];
  const float* lk2 = (const float*)d_in[12];
  const float* lambda_init = (const float*)d_in[14];

  // workspace layout (bytes, 256-aligned); total 159,655,168
  char* ws = (char*)d_ws;
  short* xb   = (short*)ws;                  // x bf16: 25216x768
  short* wqkv = (short*)(ws + 38731776);     // [Wq;Wk;Wv] bf16: 2304x768
  short* wpb  = (short*)(ws + 42270720);     // Wp' bf16: 768x768
  float* bqkv = (float*)(ws + 43450368);     // [bq;bk;bv] f32: 2304
  float* lvp  = (float*)(ws + 43459584);     // lv scalar
  short* qkv  = (short*)(ws + 43459840);     // QKV bf16: 25216x2304 (O aliases Q cols)

  cvt_f32_to_bf16<<<2048, 256, 0, stream>>>(x, xb, 19365888 / 8);
  cvt_f32_to_bf16<<<288, 256, 0, stream>>>(Wq, wqkv, 73728);
  cvt_f32_to_bf16<<<288, 256, 0, stream>>>(Wk, wqkv + 589824, 73728);
  cvt_f32_to_bf16<<<288, 256, 0, stream>>>(Wv, wqkv + 1179648, 73728);
  lv_kernel<<<1, 64, 0, stream>>>(lq1, lk1, lq2, lk2, lambda_init, lvp);
  cvt_wp_prime<<<288, 256, 0, stream>>>(Wp, lvp, wpb);  // after lv_kernel
  hipMemcpyAsync(bqkv,        bq, 768 * 4, hipMemcpyDeviceToDevice, stream);
  hipMemcpyAsync(bqkv + 768,  bk, 768 * 4, hipMemcpyDeviceToDevice, stream);
  hipMemcpyAsync(bqkv + 1536, bv, 768 * 4, hipMemcpyDeviceToDevice, stream);

  // GEMM1: QKV = xb(25216x768) @ wqkv^T(2304x768)
  gemm_bt<1><<<197 * 18, 256, 0, stream>>>(xb, 768, wqkv, bqkv, qkv, 25216, 2304, 768);
  attn_kernel<<<128 * 12, 256, 0, stream>>>(qkv);
  // GEMM2: out = attnO(25216x768, lda=2304) @ Wp'^T(768x768) + bp
  gemm_bt<0><<<197 * 6, 256, 0, stream>>>(qkv, 2304, wpb, bp, d_out, 25216, 768, 768);
}

// Round 7
// 280.259 us; speedup vs baseline: 1.2886x; 1.2886x over previous
//
#include <hip/hip_runtime.h>
#include <hip/hip_bf16.h>
#include <stdint.h>

// ---------------------------------------------------------------------------
// DifferentialBiomedCLIP: x(128,197,768) f32 -> QKV proj -> 12-head attn with
// differential combine -> output proj. bf16 MFMA (16x16x32), f32 accum.
// GEMM: proven 128x128-tile structure (607 TF measured, round 1).
// Attn: round-1 staged K+V structure, but 512-thread blocks (8 waves) share
//       ONE K/V LDS copy -> 16 waves/CU latency hiding, 1-2 q-tiles/wave.
// Combine folded into Wp' = [Wp1, Wp2 - lv*Wp1] at weight-cvt time.
// ---------------------------------------------------------------------------

typedef __attribute__((ext_vector_type(4))) float f32x4;
typedef __attribute__((ext_vector_type(8))) short s16x8;
typedef __attribute__((ext_vector_type(8))) __bf16 bf16x8;

typedef const __attribute__((address_space(1))) void* gptr_t;
typedef __attribute__((address_space(3))) void* lptr_t;

__device__ __forceinline__ f32x4 mfma16(s16x8 a, s16x8 b, f32x4 c) {
  return __builtin_amdgcn_mfma_f32_16x16x32_bf16(
      __builtin_bit_cast(bf16x8, a), __builtin_bit_cast(bf16x8, b), c, 0, 0, 0);
}

__device__ __forceinline__ short f2bf(float f) {  // RNE f32->bf16 bits
  unsigned u = __float_as_uint(f);
  u += 0x7fffu + ((u >> 16) & 1u);
  return (short)(u >> 16);
}
__device__ __forceinline__ float bf2f(short s) {
  return __uint_as_float(((unsigned)(unsigned short)s) << 16);
}

__device__ __forceinline__ void gload_lds16(const void* g, void* l) {
  // async global->LDS, 16B per lane; LDS dest = wave-uniform base + lane*16
  __builtin_amdgcn_global_load_lds((gptr_t)g, (lptr_t)l, 16, 0, 0);
}

// ---------------------------------------------------------------------------
__global__ void cvt_f32_to_bf16(const float* __restrict__ src,
                                short* __restrict__ dst, long n8) {
  long i = (long)blockIdx.x * blockDim.x + threadIdx.x;
  const long stride = (long)gridDim.x * blockDim.x;
  for (; i < n8; i += stride) {
    const float4 a = ((const float4*)src)[2 * i];
    const float4 b = ((const float4*)src)[2 * i + 1];
    s16x8 o;
    o[0] = f2bf(a.x); o[1] = f2bf(a.y); o[2] = f2bf(a.z); o[3] = f2bf(a.w);
    o[4] = f2bf(b.x); o[5] = f2bf(b.y); o[6] = f2bf(b.z); o[7] = f2bf(b.w);
    ((s16x8*)dst)[i] = o;
  }
}

// lv = mean_h(exp(min(lq1.lk1,5)) - exp(min(lq2.lk2,5))) + lambda_init
__global__ void lv_kernel(const float* __restrict__ lq1, const float* __restrict__ lk1,
                          const float* __restrict__ lq2, const float* __restrict__ lk2,
                          const float* __restrict__ lambda_init, float* __restrict__ out) {
  const int l = threadIdx.x;
  float v = 0.f;
  if (l < 6) {
    float d1 = 0.f, d2 = 0.f;
    for (int j = 0; j < 64; ++j) {
      d1 += lq1[l * 64 + j] * lk1[l * 64 + j];
      d2 += lq2[l * 64 + j] * lk2[l * 64 + j];
    }
    v = expf(fminf(d1, 5.f)) - expf(fminf(d2, 5.f));
  }
  v += __shfl_xor(v, 1, 64);
  v += __shfl_xor(v, 2, 64);
  v += __shfl_xor(v, 4, 64);
  if (l == 0) out[0] = v * (1.f / 6.f) + lambda_init[0];
}

// Wp' (bf16): cols [0,384) = Wp, cols [384,768) = Wp[:,384:] - lv*Wp[:,:384].
__global__ void cvt_wp_prime(const float* __restrict__ Wp,
                             const float* __restrict__ lvp,
                             short* __restrict__ dst) {
  const int idx = blockIdx.x * blockDim.x + threadIdx.x;  // 73728 chunks of 8
  if (idx >= 73728) return;
  const float lv = *lvp;
  const int ic = idx % 96;  // col-chunk within a row (96 x 8 = 768)
  const float4 a = ((const float4*)Wp)[2 * idx];
  const float4 b = ((const float4*)Wp)[2 * idx + 1];
  float v[8] = {a.x, a.y, a.z, a.w, b.x, b.y, b.z, b.w};
  if (ic >= 48) {  // high half: subtract lv * (same row, col-384)
    const float4 a2 = ((const float4*)Wp)[2 * idx - 96];
    const float4 b2 = ((const float4*)Wp)[2 * idx - 95];
    v[0] -= lv * a2.x; v[1] -= lv * a2.y; v[2] -= lv * a2.z; v[3] -= lv * a2.w;
    v[4] -= lv * b2.x; v[5] -= lv * b2.y; v[6] -= lv * b2.z; v[7] -= lv * b2.w;
  }
  s16x8 o;
#pragma unroll
  for (int j = 0; j < 8; ++j) o[j] = f2bf(v[j]);
  ((s16x8*)dst)[idx] = o;
}

// ---------------------------------------------------------------------------
// C[M,N] = A[M,K] * B[N,K]^T + bias ; A row stride = lda (elements), B packed.
// 128x128 tile, BK=64, 4 waves, 16x16x32 bf16 MFMA, global_load_lds staging,
// XOR chunk swizzle (pre-swizzled global source + swizzled LDS read).
template <int OUT_BF16>
__global__ __launch_bounds__(256) void gemm_bt(const short* __restrict__ A, int lda,
                                               const short* __restrict__ B,
                                               const float* __restrict__ bias,
                                               void* __restrict__ C,
                                               int M, int N, int K) {
  const int nbx = N >> 7;
  const int bx = blockIdx.x % nbx;
  const int by = blockIdx.x / nbx;
  const long m0 = (long)by << 7;
  const int n0 = bx << 7;
  __shared__ short Asm[128 * 64];
  __shared__ short Bsm[128 * 64];
  const int tid = threadIdx.x;
  const int lane = tid & 63;
  const int w = tid >> 6;
  const int wr = w >> 1, wc = w & 1;
  const int r16 = lane & 15, g = lane >> 4;
  f32x4 acc[4][4];
#pragma unroll
  for (int i = 0; i < 4; ++i)
#pragma unroll
    for (int j = 0; j < 4; ++j) acc[i][j] = f32x4{0.f, 0.f, 0.f, 0.f};

  const int nkt = K >> 6;
  for (int kt = 0; kt < nkt; ++kt) {
    __syncthreads();  // all waves done reading LDS from previous step
#pragma unroll
    for (int i = 0; i < 4; ++i) {
      const int c = i * 256 + tid;      // linear 16B chunk id (1024 per tile)
      const int row = c >> 3;           // 8 chunks per 64-elem row
      const int lc = (c & 7) ^ (row & 7);  // logical col-chunk for this slot
      gload_lds16(A + (m0 + row) * lda + (long)kt * 64 + lc * 8,
                  Asm + i * 2048 + w * 512);
      gload_lds16(B + (long)(n0 + row) * K + (long)kt * 64 + lc * 8,
                  Bsm + i * 2048 + w * 512);
    }
    asm volatile("s_waitcnt vmcnt(0)" ::: "memory");
    __syncthreads();
#pragma unroll
    for (int kk = 0; kk < 2; ++kk) {
      s16x8 av[4], bvv[4];
#pragma unroll
      for (int f = 0; f < 4; ++f) {
        const int ar = wr * 64 + f * 16 + r16;
        av[f] = *(const s16x8*)(Asm + ar * 64 + ((((kk << 2) + g) ^ (ar & 7)) << 3));
        const int br = wc * 64 + f * 16 + r16;
        bvv[f] = *(const s16x8*)(Bsm + br * 64 + ((((kk << 2) + g) ^ (br & 7)) << 3));
      }
#pragma unroll
      for (int fm = 0; fm < 4; ++fm)
#pragma unroll
        for (int fn = 0; fn < 4; ++fn)
          acc[fm][fn] = mfma16(av[fm], bvv[fn], acc[fm][fn]);
    }
  }
  // epilogue: D col=lane&15, row=(lane>>4)*4+reg
#pragma unroll
  for (int fm = 0; fm < 4; ++fm)
#pragma unroll
    for (int fn = 0; fn < 4; ++fn) {
      const int col = n0 + wc * 64 + fn * 16 + r16;
      const float bb = bias[col];
#pragma unroll
      for (int r = 0; r < 4; ++r) {
        const long row = m0 + wr * 64 + fm * 16 + g * 4 + r;
        const float v = acc[fm][fn][r] + bb;
        if (OUT_BF16) ((short*)C)[row * (long)N + col] = f2bf(v);
        else          ((float*)C)[row * (long)N + col] = v;
      }
    }
}

// ---------------------------------------------------------------------------
// Attention: one block per (b,h), 512 threads (8 waves) sharing ONE staged
// K/V LDS copy. QKV (25216 x 2304) bf16: cols [0,768)=Q, [768,1536)=K,
// [1536,2304)=V, head-major (h*64+d). Writes O in place over the Q columns
// (each wave reads its own Q rows before writing them).
// LDS: K 29952 + V 29696 + P 8192 = 67840 B -> 2 blocks/CU = 16 waves/CU.
__global__ __launch_bounds__(512, 4) void attn_kernel(short* QKV) {
  const int b = blockIdx.x / 12;
  const int h = blockIdx.x % 12;
  __shared__ short Ksm[208 * 72];   // keys padded to 208, row stride 72 elems
  __shared__ short Vsm[64 * 232];   // V transposed [d][key], stride 232 elems
  __shared__ short Psm[8][512];     // per-wave 16x32 bf16 P bounce (swizzled)
  const int tid = threadIdx.x;
  const long base = (long)b * 197 * 2304;

  for (int c = tid; c < 208 * 8; c += 512) {  // stage K
    const int key = c >> 3, dch = c & 7;
    s16x8 val = {};
    if (key < 197)
      val = *(const s16x8*)(QKV + base + (long)key * 2304 + 768 + h * 64 + dch * 8);
    *(s16x8*)(Ksm + key * 72 + dch * 8) = val;
  }
  for (int c = tid; c < 224 * 8; c += 512) {  // stage V transposed (zero pad)
    const int key = c % 224, dch = c / 224;
    s16x8 val = {};
    if (key < 197)
      val = *(const s16x8*)(QKV + base + (long)key * 2304 + 1536 + h * 64 + dch * 8);
#pragma unroll
    for (int j = 0; j < 8; ++j) Vsm[(dch * 8 + j) * 232 + key] = val[j];
  }
  __syncthreads();

  const int lane = tid & 63, w = tid >> 6;  // w = 0..7
  const int r16 = lane & 15, g = lane >> 4;
  short* psw = Psm[w];

  for (int qt = w; qt < 13; qt += 8) {  // 13 q-tiles of 16 rows, 1-2 per wave
    const int q0 = qt * 16;
    int qr = q0 + r16;
    if (qr > 196) qr = 196;  // clamp; clamped rows computed but never stored
    const s16x8 qf0 = *(const s16x8*)(QKV + base + (long)qr * 2304 + h * 64 + g * 8);
    const s16x8 qf1 = *(const s16x8*)(QKV + base + (long)qr * 2304 + h * 64 + 32 + g * 8);

    f32x4 s[13];
#pragma unroll
    for (int kt = 0; kt < 13; ++kt) s[kt] = f32x4{0.f, 0.f, 0.f, 0.f};
#pragma unroll
    for (int kt = 0; kt < 13; ++kt) {
      const int krow = kt * 16 + r16;
      const s16x8 kf0 = *(const s16x8*)(Ksm + krow * 72 + g * 8);
      const s16x8 kf1 = *(const s16x8*)(Ksm + krow * 72 + 32 + g * 8);
      s[kt] = mfma16(qf0, kf0, s[kt]);
      s[kt] = mfma16(qf1, kf1, s[kt]);
    }
    // scale, mask pad keys, row max (rows at (lane>>4)*4+reg, key=lane&15)
    float mr[4] = {-1e30f, -1e30f, -1e30f, -1e30f};
#pragma unroll
    for (int kt = 0; kt < 13; ++kt)
#pragma unroll
      for (int r = 0; r < 4; ++r) {
        float sv = s[kt][r] * 0.125f;
        if (kt == 12 && r16 >= 5) sv = -1e30f;  // keys 197..207
        s[kt][r] = sv;
        mr[r] = fmaxf(mr[r], sv);
      }
#pragma unroll
    for (int r = 0; r < 4; ++r) {
      mr[r] = fmaxf(mr[r], __shfl_xor(mr[r], 1, 64));
      mr[r] = fmaxf(mr[r], __shfl_xor(mr[r], 2, 64));
      mr[r] = fmaxf(mr[r], __shfl_xor(mr[r], 4, 64));
      mr[r] = fmaxf(mr[r], __shfl_xor(mr[r], 8, 64));
    }
    float sum[4] = {0.f, 0.f, 0.f, 0.f};
#pragma unroll
    for (int kt = 0; kt < 13; ++kt)
#pragma unroll
      for (int r = 0; r < 4; ++r) {
        const float p = __expf(s[kt][r] - mr[r]);
        s[kt][r] = p;
        sum[r] += p;
      }
#pragma unroll
    for (int r = 0; r < 4; ++r) {
      sum[r] += __shfl_xor(sum[r], 1, 64);
      sum[r] += __shfl_xor(sum[r], 2, 64);
      sum[r] += __shfl_xor(sum[r], 4, 64);
      sum[r] += __shfl_xor(sum[r], 8, 64);
    }
    // PV: bounce P through per-wave swizzled LDS tile into MFMA-A layout
    f32x4 o[4];
#pragma unroll
    for (int df = 0; df < 4; ++df) o[df] = f32x4{0.f, 0.f, 0.f, 0.f};
#pragma unroll
    for (int kb = 0; kb < 7; ++kb) {  // 7 blocks of 32 keys (last half-padded)
#pragma unroll
      for (int r = 0; r < 4; ++r) {
        const int prow = g * 4 + r;
        const int sw = (prow & 7) << 4;
        const float p1f = (kb < 6) ? s[(2 * kb + 1) % 13][r] : 0.f;
        *(short*)((char*)psw + ((prow * 64 + r16 * 2) ^ sw)) = f2bf(s[2 * kb][r]);
        *(short*)((char*)psw + ((prow * 64 + (r16 + 16) * 2) ^ sw)) = f2bf(p1f);
      }
      asm volatile("s_waitcnt lgkmcnt(0)" ::: "memory");
      const s16x8 pa =
          *(const s16x8*)((const char*)psw + ((r16 * 64 + g * 16) ^ ((r16 & 7) << 4)));
#pragma unroll
      for (int df = 0; df < 4; ++df) {
        const s16x8 vf = *(const s16x8*)(Vsm + (df * 16 + r16) * 232 + kb * 32 + g * 8);
        o[df] = mfma16(pa, vf, o[df]);
      }
    }
    float rinv[4];
#pragma unroll
    for (int r = 0; r < 4; ++r) rinv[r] = 1.f / sum[r];
#pragma unroll
    for (int df = 0; df < 4; ++df)
#pragma unroll
      for (int r = 0; r < 4; ++r) {
        const int qrow = q0 + g * 4 + r;
        if (qrow < 197)
          QKV[base + (long)qrow * 2304 + h * 64 + df * 16 + r16] =
              f2bf(o[df][r] * rinv[r]);
      }
  }
}

// ---------------------------------------------------------------------------
extern "C" void kernel_launch(void* const* d_in, const int* in_sizes, int n_in,
                              void* d_out, int out_size, void* d_ws, size_t ws_size,
                              hipStream_t stream) {
  (void)in_sizes; (void)n_in; (void)out_size; (void)ws_size;
  const float* x   = (const float*)d_in[0];
  const float* Wq  = (const float*)d_in[1];
  const float* bq  = (const float*)d_in[2];
  const float* Wk  = (const float*)d_in[3];
  const float* bk  = (const float*)d_in[4];
  const float* Wv  = (const float*)d_in[5];
  const float* bv  = (const float*)d_in[6];
  const float* Wp  = (const float*)d_in[7];
  const float* bp  = (const float*)d_in[8];
  const float* lq1 = (const float*)d_in[9];
  const float* lk1 = (const float*)d_in[10];
  const float* lq2 = (const float*)d_in[11];
  const float* lk2 = (const float*)d_in[12];
  const float* lambda_init = (const float*)d_in[14];

  // workspace layout (bytes, 256-aligned); total 159,655,168
  char* ws = (char*)d_ws;
  short* xb   = (short*)ws;                  // x bf16: 25216x768
  short* wqkv = (short*)(ws + 38731776);     // [Wq;Wk;Wv] bf16: 2304x768
  short* wpb  = (short*)(ws + 42270720);     // Wp' bf16: 768x768
  float* bqkv = (float*)(ws + 43450368);     // [bq;bk;bv] f32: 2304
  float* lvp  = (float*)(ws + 43459584);     // lv scalar
  short* qkv  = (short*)(ws + 43459840);     // QKV bf16: 25216x2304 (O aliases Q cols)

  cvt_f32_to_bf16<<<2048, 256, 0, stream>>>(x, xb, 19365888 / 8);
  cvt_f32_to_bf16<<<288, 256, 0, stream>>>(Wq, wqkv, 73728);
  cvt_f32_to_bf16<<<288, 256, 0, stream>>>(Wk, wqkv + 589824, 73728);
  cvt_f32_to_bf16<<<288, 256, 0, stream>>>(Wv, wqkv + 1179648, 73728);
  lv_kernel<<<1, 64, 0, stream>>>(lq1, lk1, lq2, lk2, lambda_init, lvp);
  cvt_wp_prime<<<288, 256, 0, stream>>>(Wp, lvp, wpb);  // after lv_kernel
  hipMemcpyAsync(bqkv,        bq, 768 * 4, hipMemcpyDeviceToDevice, stream);
  hipMemcpyAsync(bqkv + 768,  bk, 768 * 4, hipMemcpyDeviceToDevice, stream);
  hipMemcpyAsync(bqkv + 1536, bv, 768 * 4, hipMemcpyDeviceToDevice, stream);

  // GEMM1: QKV = xb(25216x768) @ wqkv^T(2304x768)
  gemm_bt<1><<<197 * 18, 256, 0, stream>>>(xb, 768, wqkv, bqkv, qkv, 25216, 2304, 768);
  attn_kernel<<<128 * 12, 512, 0, stream>>>(qkv);
  // GEMM2: out = attnO(25216x768, lda=2304) @ Wp'^T(768x768) + bp
  gemm_bt<0><<<197 * 6, 256, 0, stream>>>(qkv, 2304, wpb, bp, d_out, 25216, 768, 768);
}

// Round 8
// 262.491 us; speedup vs baseline: 1.3758x; 1.0677x over previous
//
#include <hip/hip_runtime.h>
#include <hip/hip_bf16.h>
#include <stdint.h>

// ---------------------------------------------------------------------------
// DifferentialBiomedCLIP: x(128,197,768) f32 -> QKV proj -> 12-head attn with
// differential combine -> output proj. bf16 MFMA (16x16x32), f32 accum.
// GEMM: proven 128x128-tile structure + bijective XCD swizzle (T1) so the 18
//       N-blocks sharing an A-panel land on one XCD's L2.
// Attn: 512-thr blocks share one K/V LDS copy; PV P-bounce DOUBLE-BUFFERED
//       (write kb+1 overlaps MFMA of kb; DS ops in-order per wave).
// Combine folded into Wp' = [Wp1, Wp2 - lv*Wp1] at weight-cvt time.
// ---------------------------------------------------------------------------

typedef __attribute__((ext_vector_type(4))) float f32x4;
typedef __attribute__((ext_vector_type(8))) short s16x8;
typedef __attribute__((ext_vector_type(8))) __bf16 bf16x8;

typedef const __attribute__((address_space(1))) void* gptr_t;
typedef __attribute__((address_space(3))) void* lptr_t;

__device__ __forceinline__ f32x4 mfma16(s16x8 a, s16x8 b, f32x4 c) {
  return __builtin_amdgcn_mfma_f32_16x16x32_bf16(
      __builtin_bit_cast(bf16x8, a), __builtin_bit_cast(bf16x8, b), c, 0, 0, 0);
}

__device__ __forceinline__ short f2bf(float f) {  // RNE f32->bf16 bits
  unsigned u = __float_as_uint(f);
  u += 0x7fffu + ((u >> 16) & 1u);
  return (short)(u >> 16);
}
__device__ __forceinline__ float bf2f(short s) {
  return __uint_as_float(((unsigned)(unsigned short)s) << 16);
}

__device__ __forceinline__ void gload_lds16(const void* g, void* l) {
  // async global->LDS, 16B per lane; LDS dest = wave-uniform base + lane*16
  __builtin_amdgcn_global_load_lds((gptr_t)g, (lptr_t)l, 16, 0, 0);
}

// ---------------------------------------------------------------------------
__global__ void cvt_f32_to_bf16(const float* __restrict__ src,
                                short* __restrict__ dst, long n8) {
  long i = (long)blockIdx.x * blockDim.x + threadIdx.x;
  const long stride = (long)gridDim.x * blockDim.x;
  for (; i < n8; i += stride) {
    const float4 a = ((const float4*)src)[2 * i];
    const float4 b = ((const float4*)src)[2 * i + 1];
    s16x8 o;
    o[0] = f2bf(a.x); o[1] = f2bf(a.y); o[2] = f2bf(a.z); o[3] = f2bf(a.w);
    o[4] = f2bf(b.x); o[5] = f2bf(b.y); o[6] = f2bf(b.z); o[7] = f2bf(b.w);
    ((s16x8*)dst)[i] = o;
  }
}

// lv = mean_h(exp(min(lq1.lk1,5)) - exp(min(lq2.lk2,5))) + lambda_init
__global__ void lv_kernel(const float* __restrict__ lq1, const float* __restrict__ lk1,
                          const float* __restrict__ lq2, const float* __restrict__ lk2,
                          const float* __restrict__ lambda_init, float* __restrict__ out) {
  const int l = threadIdx.x;
  float v = 0.f;
  if (l < 6) {
    float d1 = 0.f, d2 = 0.f;
    for (int j = 0; j < 64; ++j) {
      d1 += lq1[l * 64 + j] * lk1[l * 64 + j];
      d2 += lq2[l * 64 + j] * lk2[l * 64 + j];
    }
    v = expf(fminf(d1, 5.f)) - expf(fminf(d2, 5.f));
  }
  v += __shfl_xor(v, 1, 64);
  v += __shfl_xor(v, 2, 64);
  v += __shfl_xor(v, 4, 64);
  if (l == 0) out[0] = v * (1.f / 6.f) + lambda_init[0];
}

// Wp' (bf16): cols [0,384) = Wp, cols [384,768) = Wp[:,384:] - lv*Wp[:,:384].
__global__ void cvt_wp_prime(const float* __restrict__ Wp,
                             const float* __restrict__ lvp,
                             short* __restrict__ dst) {
  const int idx = blockIdx.x * blockDim.x + threadIdx.x;  // 73728 chunks of 8
  if (idx >= 73728) return;
  const float lv = *lvp;
  const int ic = idx % 96;  // col-chunk within a row (96 x 8 = 768)
  const float4 a = ((const float4*)Wp)[2 * idx];
  const float4 b = ((const float4*)Wp)[2 * idx + 1];
  float v[8] = {a.x, a.y, a.z, a.w, b.x, b.y, b.z, b.w};
  if (ic >= 48) {  // high half: subtract lv * (same row, col-384)
    const float4 a2 = ((const float4*)Wp)[2 * idx - 96];
    const float4 b2 = ((const float4*)Wp)[2 * idx - 95];
    v[0] -= lv * a2.x; v[1] -= lv * a2.y; v[2] -= lv * a2.z; v[3] -= lv * a2.w;
    v[4] -= lv * b2.x; v[5] -= lv * b2.y; v[6] -= lv * b2.z; v[7] -= lv * b2.w;
  }
  s16x8 o;
#pragma unroll
  for (int j = 0; j < 8; ++j) o[j] = f2bf(v[j]);
  ((s16x8*)dst)[idx] = o;
}

// ---------------------------------------------------------------------------
// C[M,N] = A[M,K] * B[N,K]^T + bias ; A row stride = lda (elements), B packed.
// 128x128 tile, BK=64, 4 waves, 16x16x32 bf16 MFMA, global_load_lds staging,
// XOR chunk swizzle. T1: bijective chunked XCD swizzle so the nbx consecutive
// blocks sharing an A row-panel co-locate on one XCD's L2.
template <int OUT_BF16>
__global__ __launch_bounds__(256) void gemm_bt(const short* __restrict__ A, int lda,
                                               const short* __restrict__ B,
                                               const float* __restrict__ bias,
                                               void* __restrict__ C,
                                               int M, int N, int K) {
  const int nbx = N >> 7;
  // bijective XCD swizzle (m204 form, any grid size)
  const int nwg = gridDim.x;
  const int qq = nwg >> 3, rr = nwg & 7;
  const int xcd = blockIdx.x & 7, pos = blockIdx.x >> 3;
  const int wg = (xcd < rr ? xcd * (qq + 1) : rr * (qq + 1) + (xcd - rr) * qq) + pos;
  const int bx = wg % nbx;
  const int by = wg / nbx;
  const long m0 = (long)by << 7;
  const int n0 = bx << 7;
  __shared__ short Asm[128 * 64];
  __shared__ short Bsm[128 * 64];
  const int tid = threadIdx.x;
  const int lane = tid & 63;
  const int w = tid >> 6;
  const int wr = w >> 1, wc = w & 1;
  const int r16 = lane & 15, g = lane >> 4;
  f32x4 acc[4][4];
#pragma unroll
  for (int i = 0; i < 4; ++i)
#pragma unroll
    for (int j = 0; j < 4; ++j) acc[i][j] = f32x4{0.f, 0.f, 0.f, 0.f};

  const int nkt = K >> 6;
  for (int kt = 0; kt < nkt; ++kt) {
    __syncthreads();  // all waves done reading LDS from previous step
#pragma unroll
    for (int i = 0; i < 4; ++i) {
      const int c = i * 256 + tid;      // linear 16B chunk id (1024 per tile)
      const int row = c >> 3;           // 8 chunks per 64-elem row
      const int lc = (c & 7) ^ (row & 7);  // logical col-chunk for this slot
      gload_lds16(A + (m0 + row) * lda + (long)kt * 64 + lc * 8,
                  Asm + i * 2048 + w * 512);
      gload_lds16(B + (long)(n0 + row) * K + (long)kt * 64 + lc * 8,
                  Bsm + i * 2048 + w * 512);
    }
    asm volatile("s_waitcnt vmcnt(0)" ::: "memory");
    __syncthreads();
#pragma unroll
    for (int kk = 0; kk < 2; ++kk) {
      s16x8 av[4], bvv[4];
#pragma unroll
      for (int f = 0; f < 4; ++f) {
        const int ar = wr * 64 + f * 16 + r16;
        av[f] = *(const s16x8*)(Asm + ar * 64 + ((((kk << 2) + g) ^ (ar & 7)) << 3));
        const int br = wc * 64 + f * 16 + r16;
        bvv[f] = *(const s16x8*)(Bsm + br * 64 + ((((kk << 2) + g) ^ (br & 7)) << 3));
      }
#pragma unroll
      for (int fm = 0; fm < 4; ++fm)
#pragma unroll
        for (int fn = 0; fn < 4; ++fn)
          acc[fm][fn] = mfma16(av[fm], bvv[fn], acc[fm][fn]);
    }
  }
  // epilogue: D col=lane&15, row=(lane>>4)*4+reg
#pragma unroll
  for (int fm = 0; fm < 4; ++fm)
#pragma unroll
    for (int fn = 0; fn < 4; ++fn) {
      const int col = n0 + wc * 64 + fn * 16 + r16;
      const float bb = bias[col];
#pragma unroll
      for (int r = 0; r < 4; ++r) {
        const long row = m0 + wr * 64 + fm * 16 + g * 4 + r;
        const float v = acc[fm][fn][r] + bb;
        if (OUT_BF16) ((short*)C)[row * (long)N + col] = f2bf(v);
        else          ((float*)C)[row * (long)N + col] = v;
      }
    }
}

// ---------------------------------------------------------------------------
// Attention: one block per (b,h), 512 threads (8 waves) sharing ONE staged
// K/V LDS copy. QKV (25216 x 2304) bf16: cols [0,768)=Q, [768,1536)=K,
// [1536,2304)=V, head-major (h*64+d). Writes O in place over the Q columns
// (each wave reads its own Q rows before writing them).
// PV P-bounce is double-buffered: P(kb+1) writes overlap MFMA(kb); DS ops
// execute in-order per wave so no explicit wait between write(kb)/read(kb).
// LDS: K 29952 + V 29696 + P 16384 = 76032 B -> 2 blocks/CU = 16 waves/CU.
__global__ __launch_bounds__(512, 4) void attn_kernel(short* QKV) {
  const int b = blockIdx.x / 12;
  const int h = blockIdx.x % 12;
  __shared__ short Ksm[208 * 72];      // keys padded to 208, row stride 72
  __shared__ short Vsm[64 * 232];      // V transposed [d][key], stride 232
  __shared__ short Psm[8][2][512];     // per-wave DOUBLE-BUFFERED 16x32 P tile
  const int tid = threadIdx.x;
  const long base = (long)b * 197 * 2304;

  for (int c = tid; c < 208 * 8; c += 512) {  // stage K
    const int key = c >> 3, dch = c & 7;
    s16x8 val = {};
    if (key < 197)
      val = *(const s16x8*)(QKV + base + (long)key * 2304 + 768 + h * 64 + dch * 8);
    *(s16x8*)(Ksm + key * 72 + dch * 8) = val;
  }
  for (int c = tid; c < 224 * 8; c += 512) {  // stage V transposed (zero pad)
    const int key = c % 224, dch = c / 224;
    s16x8 val = {};
    if (key < 197)
      val = *(const s16x8*)(QKV + base + (long)key * 2304 + 1536 + h * 64 + dch * 8);
#pragma unroll
    for (int j = 0; j < 8; ++j) Vsm[(dch * 8 + j) * 232 + key] = val[j];
  }
  __syncthreads();

  const int lane = tid & 63, w = tid >> 6;  // w = 0..7
  const int r16 = lane & 15, g = lane >> 4;
  char* psw = (char*)Psm[w];

  for (int qt = w; qt < 13; qt += 8) {  // 13 q-tiles of 16 rows, 1-2 per wave
    const int q0 = qt * 16;
    int qr = q0 + r16;
    if (qr > 196) qr = 196;  // clamp; clamped rows computed but never stored
    const s16x8 qf0 = *(const s16x8*)(QKV + base + (long)qr * 2304 + h * 64 + g * 8);
    const s16x8 qf1 = *(const s16x8*)(QKV + base + (long)qr * 2304 + h * 64 + 32 + g * 8);

    f32x4 s[13];
#pragma unroll
    for (int kt = 0; kt < 13; ++kt) s[kt] = f32x4{0.f, 0.f, 0.f, 0.f};
#pragma unroll
    for (int kt = 0; kt < 13; ++kt) {
      const int krow = kt * 16 + r16;
      const s16x8 kf0 = *(const s16x8*)(Ksm + krow * 72 + g * 8);
      const s16x8 kf1 = *(const s16x8*)(Ksm + krow * 72 + 32 + g * 8);
      s[kt] = mfma16(qf0, kf0, s[kt]);
      s[kt] = mfma16(qf1, kf1, s[kt]);
    }
    // scale, mask pad keys, row max (rows at (lane>>4)*4+reg, key=lane&15)
    float mr[4] = {-1e30f, -1e30f, -1e30f, -1e30f};
#pragma unroll
    for (int kt = 0; kt < 13; ++kt)
#pragma unroll
      for (int r = 0; r < 4; ++r) {
        float sv = s[kt][r] * 0.125f;
        if (kt == 12 && r16 >= 5) sv = -1e30f;  // keys 197..207
        s[kt][r] = sv;
        mr[r] = fmaxf(mr[r], sv);
      }
#pragma unroll
    for (int r = 0; r < 4; ++r) {
      mr[r] = fmaxf(mr[r], __shfl_xor(mr[r], 1, 64));
      mr[r] = fmaxf(mr[r], __shfl_xor(mr[r], 2, 64));
      mr[r] = fmaxf(mr[r], __shfl_xor(mr[r], 4, 64));
      mr[r] = fmaxf(mr[r], __shfl_xor(mr[r], 8, 64));
    }
    float sum[4] = {0.f, 0.f, 0.f, 0.f};
#pragma unroll
    for (int kt = 0; kt < 13; ++kt)
#pragma unroll
      for (int r = 0; r < 4; ++r) {
        const float p = __expf(s[kt][r] - mr[r]);
        s[kt][r] = p;
        sum[r] += p;
      }
#pragma unroll
    for (int r = 0; r < 4; ++r) {
      sum[r] += __shfl_xor(sum[r], 1, 64);
      sum[r] += __shfl_xor(sum[r], 2, 64);
      sum[r] += __shfl_xor(sum[r], 4, 64);
      sum[r] += __shfl_xor(sum[r], 8, 64);
    }
    // PV with double-buffered P bounce.
    f32x4 o[4];
#pragma unroll
    for (int df = 0; df < 4; ++df) o[df] = f32x4{0.f, 0.f, 0.f, 0.f};
    // prologue: write P(kb=0) -> buf 0
#pragma unroll
    for (int r = 0; r < 4; ++r) {
      const int prow = g * 4 + r;
      const int sw = (prow & 7) << 4;
      *(short*)(psw + ((prow * 64 + r16 * 2) ^ sw)) = f2bf(s[0][r]);
      *(short*)(psw + ((prow * 64 + (r16 + 16) * 2) ^ sw)) = f2bf(s[1][r]);
    }
#pragma unroll
    for (int kb = 0; kb < 7; ++kb) {  // 7 blocks of 32 keys (last half-padded)
      char* bufr = psw + ((kb & 1) << 10);
      char* bufw = psw + (((kb & 1) ^ 1) << 10);
      // read P(kb) — in-order DS guarantees the buf was written
      const s16x8 pa =
          *(const s16x8*)(bufr + ((r16 * 64 + g * 16) ^ ((r16 & 7) << 4)));
      if (kb < 6) {  // write P(kb+1) into the other buffer (overlaps MFMA)
#pragma unroll
        for (int r = 0; r < 4; ++r) {
          const int prow = g * 4 + r;
          const int sw = (prow & 7) << 4;
          const float p0f = s[2 * kb + 2][r];
          const float p1f = (kb < 5) ? s[2 * kb + 3][r] : 0.f;
          *(short*)(bufw + ((prow * 64 + r16 * 2) ^ sw)) = f2bf(p0f);
          *(short*)(bufw + ((prow * 64 + (r16 + 16) * 2) ^ sw)) = f2bf(p1f);
        }
      }
#pragma unroll
      for (int df = 0; df < 4; ++df) {
        const s16x8 vf = *(const s16x8*)(Vsm + (df * 16 + r16) * 232 + kb * 32 + g * 8);
        o[df] = mfma16(pa, vf, o[df]);
      }
    }
    float rinv[4];
#pragma unroll
    for (int r = 0; r < 4; ++r) rinv[r] = 1.f / sum[r];
#pragma unroll
    for (int df = 0; df < 4; ++df)
#pragma unroll
      for (int r = 0; r < 4; ++r) {
        const int qrow = q0 + g * 4 + r;
        if (qrow < 197)
          QKV[base + (long)qrow * 2304 + h * 64 + df * 16 + r16] =
              f2bf(o[df][r] * rinv[r]);
      }
  }
}

// ---------------------------------------------------------------------------
extern "C" void kernel_launch(void* const* d_in, const int* in_sizes, int n_in,
                              void* d_out, int out_size, void* d_ws, size_t ws_size,
                              hipStream_t stream) {
  (void)in_sizes; (void)n_in; (void)out_size; (void)ws_size;
  const float* x   = (const float*)d_in[0];
  const float* Wq  = (const float*)d_in[1];
  const float* bq  = (const float*)d_in[2];
  const float* Wk  = (const float*)d_in[3];
  const float* bk  = (const float*)d_in[4];
  const float* Wv  = (const float*)d_in[5];
  const float* bv  = (const float*)d_in[6];
  const float* Wp  = (const float*)d_in[7];
  const float* bp  = (const float*)d_in[8];
  const float* lq1 = (const float*)d_in[9];
  const float* lk1 = (const float*)d_in[10];
  const float* lq2 = (const float*)d_in[11];
  const float* lk2 = (const float*)d_in[12];
  const float* lambda_init = (const float*)d_in[14];

  // workspace layout (bytes, 256-aligned); total 159,655,168
  char* ws = (char*)d_ws;
  short* xb   = (short*)ws;                  // x bf16: 25216x768
  short* wqkv = (short*)(ws + 38731776);     // [Wq;Wk;Wv] bf16: 2304x768
  short* wpb  = (short*)(ws + 42270720);     // Wp' bf16: 768x768
  float* bqkv = (float*)(ws + 43450368);     // [bq;bk;bv] f32: 2304
  float* lvp  = (float*)(ws + 43459584);     // lv scalar
  short* qkv  = (short*)(ws + 43459840);     // QKV bf16: 25216x2304 (O aliases Q cols)

  cvt_f32_to_bf16<<<2048, 256, 0, stream>>>(x, xb, 19365888 / 8);
  cvt_f32_to_bf16<<<288, 256, 0, stream>>>(Wq, wqkv, 73728);
  cvt_f32_to_bf16<<<288, 256, 0, stream>>>(Wk, wqkv + 589824, 73728);
  cvt_f32_to_bf16<<<288, 256, 0, stream>>>(Wv, wqkv + 1179648, 73728);
  lv_kernel<<<1, 64, 0, stream>>>(lq1, lk1, lq2, lk2, lambda_init, lvp);
  cvt_wp_prime<<<288, 256, 0, stream>>>(Wp, lvp, wpb);  // after lv_kernel
  hipMemcpyAsync(bqkv,        bq, 768 * 4, hipMemcpyDeviceToDevice, stream);
  hipMemcpyAsync(bqkv + 768,  bk, 768 * 4, hipMemcpyDeviceToDevice, stream);
  hipMemcpyAsync(bqkv + 1536, bv, 768 * 4, hipMemcpyDeviceToDevice, stream);

  // GEMM1: QKV = xb(25216x768) @ wqkv^T(2304x768)
  gemm_bt<1><<<197 * 18, 256, 0, stream>>>(xb, 768, wqkv, bqkv, qkv, 25216, 2304, 768);
  attn_kernel<<<128 * 12, 512, 0, stream>>>(qkv);
  // GEMM2: out = attnO(25216x768, lda=2304) @ Wp'^T(768x768) + bp
  gemm_bt<0><<<197 * 6, 256, 0, stream>>>(qkv, 2304, wpb, bp, d_out, 25216, 768, 768);
}

// Round 9
// 242.440 us; speedup vs baseline: 1.4896x; 1.0827x over previous
//
#include <hip/hip_runtime.h>
#include <hip/hip_bf16.h>
#include <stdint.h>

// ---------------------------------------------------------------------------
// DifferentialBiomedCLIP: x(128,197,768) f32 -> QKV proj -> 12-head attn with
// differential combine -> output proj. bf16 MFMA (16x16x32), f32 accum.
// GEMM: proven 128x128-tile structure + T1 bijective XCD swizzle; K-loop
//       fully unrolled via template NKT=12 (stage addresses fold to base+imm).
// Attn: 1024-thr blocks (16 waves), one shared K/V LDS copy, one q-tile per
//       wave, per-wave double-buffered P bounce.
// Combine folded into Wp' = [Wp1, Wp2 - lv*Wp1] at weight-cvt time.
// ---------------------------------------------------------------------------

typedef __attribute__((ext_vector_type(4))) float f32x4;
typedef __attribute__((ext_vector_type(8))) short s16x8;
typedef __attribute__((ext_vector_type(8))) __bf16 bf16x8;

typedef const __attribute__((address_space(1))) void* gptr_t;
typedef __attribute__((address_space(3))) void* lptr_t;

__device__ __forceinline__ f32x4 mfma16(s16x8 a, s16x8 b, f32x4 c) {
  return __builtin_amdgcn_mfma_f32_16x16x32_bf16(
      __builtin_bit_cast(bf16x8, a), __builtin_bit_cast(bf16x8, b), c, 0, 0, 0);
}

__device__ __forceinline__ short f2bf(float f) {  // RNE f32->bf16 bits
  unsigned u = __float_as_uint(f);
  u += 0x7fffu + ((u >> 16) & 1u);
  return (short)(u >> 16);
}
__device__ __forceinline__ float bf2f(short s) {
  return __uint_as_float(((unsigned)(unsigned short)s) << 16);
}

__device__ __forceinline__ void gload_lds16(const void* g, void* l) {
  // async global->LDS, 16B per lane; LDS dest = wave-uniform base + lane*16
  __builtin_amdgcn_global_load_lds((gptr_t)g, (lptr_t)l, 16, 0, 0);
}

// ---------------------------------------------------------------------------
__global__ void cvt_f32_to_bf16(const float* __restrict__ src,
                                short* __restrict__ dst, long n8) {
  long i = (long)blockIdx.x * blockDim.x + threadIdx.x;
  const long stride = (long)gridDim.x * blockDim.x;
  for (; i < n8; i += stride) {
    const float4 a = ((const float4*)src)[2 * i];
    const float4 b = ((const float4*)src)[2 * i + 1];
    s16x8 o;
    o[0] = f2bf(a.x); o[1] = f2bf(a.y); o[2] = f2bf(a.z); o[3] = f2bf(a.w);
    o[4] = f2bf(b.x); o[5] = f2bf(b.y); o[6] = f2bf(b.z); o[7] = f2bf(b.w);
    ((s16x8*)dst)[i] = o;
  }
}

// lv = mean_h(exp(min(lq1.lk1,5)) - exp(min(lq2.lk2,5))) + lambda_init
__global__ void lv_kernel(const float* __restrict__ lq1, const float* __restrict__ lk1,
                          const float* __restrict__ lq2, const float* __restrict__ lk2,
                          const float* __restrict__ lambda_init, float* __restrict__ out) {
  const int l = threadIdx.x;
  float v = 0.f;
  if (l < 6) {
    float d1 = 0.f, d2 = 0.f;
    for (int j = 0; j < 64; ++j) {
      d1 += lq1[l * 64 + j] * lk1[l * 64 + j];
      d2 += lq2[l * 64 + j] * lk2[l * 64 + j];
    }
    v = expf(fminf(d1, 5.f)) - expf(fminf(d2, 5.f));
  }
  v += __shfl_xor(v, 1, 64);
  v += __shfl_xor(v, 2, 64);
  v += __shfl_xor(v, 4, 64);
  if (l == 0) out[0] = v * (1.f / 6.f) + lambda_init[0];
}

// Wp' (bf16): cols [0,384) = Wp, cols [384,768) = Wp[:,384:] - lv*Wp[:,:384].
__global__ void cvt_wp_prime(const float* __restrict__ Wp,
                             const float* __restrict__ lvp,
                             short* __restrict__ dst) {
  const int idx = blockIdx.x * blockDim.x + threadIdx.x;  // 73728 chunks of 8
  if (idx >= 73728) return;
  const float lv = *lvp;
  const int ic = idx % 96;  // col-chunk within a row (96 x 8 = 768)
  const float4 a = ((const float4*)Wp)[2 * idx];
  const float4 b = ((const float4*)Wp)[2 * idx + 1];
  float v[8] = {a.x, a.y, a.z, a.w, b.x, b.y, b.z, b.w};
  if (ic >= 48) {  // high half: subtract lv * (same row, col-384)
    const float4 a2 = ((const float4*)Wp)[2 * idx - 96];
    const float4 b2 = ((const float4*)Wp)[2 * idx - 95];
    v[0] -= lv * a2.x; v[1] -= lv * a2.y; v[2] -= lv * a2.z; v[3] -= lv * a2.w;
    v[4] -= lv * b2.x; v[5] -= lv * b2.y; v[6] -= lv * b2.z; v[7] -= lv * b2.w;
  }
  s16x8 o;
#pragma unroll
  for (int j = 0; j < 8; ++j) o[j] = f2bf(v[j]);
  ((s16x8*)dst)[idx] = o;
}

// ---------------------------------------------------------------------------
// C[M,N] = A[M,K] * B[N,K]^T + bias ; A row stride = lda (elements), B packed.
// 128x128 tile, BK=64, 4 waves, 16x16x32 bf16 MFMA, global_load_lds staging,
// XOR chunk swizzle, T1 bijective XCD swizzle. K = NKT*64 compile-time ->
// full unroll; per-iteration global offsets become 13-bit immediates.
template <int OUT_BF16, int NKT>
__global__ __launch_bounds__(256) void gemm_bt(const short* __restrict__ A, int lda,
                                               const short* __restrict__ B,
                                               const float* __restrict__ bias,
                                               void* __restrict__ C,
                                               int M, int N) {
  const int K = NKT * 64;
  const int nbx = N >> 7;
  // bijective XCD swizzle (m204 form, any grid size)
  const int nwg = gridDim.x;
  const int qq = nwg >> 3, rr = nwg & 7;
  const int xcd = blockIdx.x & 7, pos = blockIdx.x >> 3;
  const int wg = (xcd < rr ? xcd * (qq + 1) : rr * (qq + 1) + (xcd - rr) * qq) + pos;
  const int bx = wg % nbx;
  const int by = wg / nbx;
  const long m0 = (long)by << 7;
  const int n0 = bx << 7;
  __shared__ short Asm[128 * 64];
  __shared__ short Bsm[128 * 64];
  const int tid = threadIdx.x;
  const int lane = tid & 63;
  const int w = tid >> 6;
  const int wr = w >> 1, wc = w & 1;
  const int r16 = lane & 15, g = lane >> 4;

  // loop-invariant staging bases (per-thread); kt adds a constant immediate
  const short* abase[4];
  const short* bbase[4];
#pragma unroll
  for (int i = 0; i < 4; ++i) {
    const int c = i * 256 + tid;
    const int row = c >> 3;
    const int lc = (c & 7) ^ (row & 7);  // XOR chunk swizzle (involution)
    abase[i] = A + (m0 + row) * (long)lda + lc * 8;
    bbase[i] = B + (long)(n0 + row) * (long)K + lc * 8;
  }

  f32x4 acc[4][4];
#pragma unroll
  for (int i = 0; i < 4; ++i)
#pragma unroll
    for (int j = 0; j < 4; ++j) acc[i][j] = f32x4{0.f, 0.f, 0.f, 0.f};

#pragma unroll
  for (int kt = 0; kt < NKT; ++kt) {
    __syncthreads();  // all waves done reading LDS from previous step
#pragma unroll
    for (int i = 0; i < 4; ++i) {
      gload_lds16(abase[i] + kt * 64, Asm + i * 2048 + w * 512);
      gload_lds16(bbase[i] + kt * 64, Bsm + i * 2048 + w * 512);
    }
    asm volatile("s_waitcnt vmcnt(0)" ::: "memory");
    __syncthreads();
#pragma unroll
    for (int kk = 0; kk < 2; ++kk) {
      s16x8 av[4], bvv[4];
#pragma unroll
      for (int f = 0; f < 4; ++f) {
        const int ar = wr * 64 + f * 16 + r16;
        av[f] = *(const s16x8*)(Asm + ar * 64 + ((((kk << 2) + g) ^ (ar & 7)) << 3));
        const int br = wc * 64 + f * 16 + r16;
        bvv[f] = *(const s16x8*)(Bsm + br * 64 + ((((kk << 2) + g) ^ (br & 7)) << 3));
      }
#pragma unroll
      for (int fm = 0; fm < 4; ++fm)
#pragma unroll
        for (int fn = 0; fn < 4; ++fn)
          acc[fm][fn] = mfma16(av[fm], bvv[fn], acc[fm][fn]);
    }
  }
  // epilogue: D col=lane&15, row=(lane>>4)*4+reg
#pragma unroll
  for (int fm = 0; fm < 4; ++fm)
#pragma unroll
    for (int fn = 0; fn < 4; ++fn) {
      const int col = n0 + wc * 64 + fn * 16 + r16;
      const float bb = bias[col];
#pragma unroll
      for (int r = 0; r < 4; ++r) {
        const long row = m0 + wr * 64 + fm * 16 + g * 4 + r;
        const float v = acc[fm][fn][r] + bb;
        if (OUT_BF16) ((short*)C)[row * (long)N + col] = f2bf(v);
        else          ((float*)C)[row * (long)N + col] = v;
      }
    }
}

// ---------------------------------------------------------------------------
// Attention: one block per (b,h), 1024 threads (16 waves) sharing ONE staged
// K/V LDS copy; waves 0..12 each own one 16-row q-tile. QKV (25216 x 2304)
// bf16: cols [0,768)=Q, [768,1536)=K, [1536,2304)=V, head-major (h*64+d).
// Writes O in place over the Q columns (each wave reads its own Q rows before
// writing them; no other wave touches those rows).
// PV P-bounce double-buffered per wave (DS ops in-order per wave).
// LDS: K 29952 + V 29696 + P 32768 = 92416 B -> 1 block/CU = 16 waves/CU.
// No barriers inside the q-tile loop, so idle waves (13..15) exit safely.
__global__ __launch_bounds__(1024, 4) void attn_kernel(short* QKV) {
  const int b = blockIdx.x / 12;
  const int h = blockIdx.x % 12;
  __shared__ short Ksm[208 * 72];      // keys padded to 208, row stride 72
  __shared__ short Vsm[64 * 232];      // V transposed [d][key], stride 232
  __shared__ short Psm[16][2][512];    // per-wave double-buffered 16x32 P tile
  const int tid = threadIdx.x;
  const long base = (long)b * 197 * 2304;

  for (int c = tid; c < 208 * 8; c += 1024) {  // stage K
    const int key = c >> 3, dch = c & 7;
    s16x8 val = {};
    if (key < 197)
      val = *(const s16x8*)(QKV + base + (long)key * 2304 + 768 + h * 64 + dch * 8);
    *(s16x8*)(Ksm + key * 72 + dch * 8) = val;
  }
  for (int c = tid; c < 224 * 8; c += 1024) {  // stage V transposed (zero pad)
    const int key = c % 224, dch = c / 224;
    s16x8 val = {};
    if (key < 197)
      val = *(const s16x8*)(QKV + base + (long)key * 2304 + 1536 + h * 64 + dch * 8);
#pragma unroll
    for (int j = 0; j < 8; ++j) Vsm[(dch * 8 + j) * 232 + key] = val[j];
  }
  __syncthreads();

  const int lane = tid & 63, w = tid >> 6;  // w = 0..15
  const int r16 = lane & 15, g = lane >> 4;
  char* psw = (char*)Psm[w];

  if (w < 13) {  // one 16-row q-tile per wave; waves 13-15 idle (no barriers)
    const int q0 = w * 16;
    int qr = q0 + r16;
    if (qr > 196) qr = 196;  // clamp; clamped rows computed but never stored
    const s16x8 qf0 = *(const s16x8*)(QKV + base + (long)qr * 2304 + h * 64 + g * 8);
    const s16x8 qf1 = *(const s16x8*)(QKV + base + (long)qr * 2304 + h * 64 + 32 + g * 8);

    f32x4 s[13];
#pragma unroll
    for (int kt = 0; kt < 13; ++kt) s[kt] = f32x4{0.f, 0.f, 0.f, 0.f};
#pragma unroll
    for (int kt = 0; kt < 13; ++kt) {
      const int krow = kt * 16 + r16;
      const s16x8 kf0 = *(const s16x8*)(Ksm + krow * 72 + g * 8);
      const s16x8 kf1 = *(const s16x8*)(Ksm + krow * 72 + 32 + g * 8);
      s[kt] = mfma16(qf0, kf0, s[kt]);
      s[kt] = mfma16(qf1, kf1, s[kt]);
    }
    // scale, mask pad keys, row max (rows at (lane>>4)*4+reg, key=lane&15)
    float mr[4] = {-1e30f, -1e30f, -1e30f, -1e30f};
#pragma unroll
    for (int kt = 0; kt < 13; ++kt)
#pragma unroll
      for (int r = 0; r < 4; ++r) {
        float sv = s[kt][r] * 0.125f;
        if (kt == 12 && r16 >= 5) sv = -1e30f;  // keys 197..207
        s[kt][r] = sv;
        mr[r] = fmaxf(mr[r], sv);
      }
#pragma unroll
    for (int r = 0; r < 4; ++r) {
      mr[r] = fmaxf(mr[r], __shfl_xor(mr[r], 1, 64));
      mr[r] = fmaxf(mr[r], __shfl_xor(mr[r], 2, 64));
      mr[r] = fmaxf(mr[r], __shfl_xor(mr[r], 4, 64));
      mr[r] = fmaxf(mr[r], __shfl_xor(mr[r], 8, 64));
    }
    float sum[4] = {0.f, 0.f, 0.f, 0.f};
#pragma unroll
    for (int kt = 0; kt < 13; ++kt)
#pragma unroll
      for (int r = 0; r < 4; ++r) {
        const float p = __expf(s[kt][r] - mr[r]);
        s[kt][r] = p;
        sum[r] += p;
      }
#pragma unroll
    for (int r = 0; r < 4; ++r) {
      sum[r] += __shfl_xor(sum[r], 1, 64);
      sum[r] += __shfl_xor(sum[r], 2, 64);
      sum[r] += __shfl_xor(sum[r], 4, 64);
      sum[r] += __shfl_xor(sum[r], 8, 64);
    }
    // PV with double-buffered P bounce.
    f32x4 o[4];
#pragma unroll
    for (int df = 0; df < 4; ++df) o[df] = f32x4{0.f, 0.f, 0.f, 0.f};
    // prologue: write P(kb=0) -> buf 0
#pragma unroll
    for (int r = 0; r < 4; ++r) {
      const int prow = g * 4 + r;
      const int sw = (prow & 7) << 4;
      *(short*)(psw + ((prow * 64 + r16 * 2) ^ sw)) = f2bf(s[0][r]);
      *(short*)(psw + ((prow * 64 + (r16 + 16) * 2) ^ sw)) = f2bf(s[1][r]);
    }
#pragma unroll
    for (int kb = 0; kb < 7; ++kb) {  // 7 blocks of 32 keys (last half-padded)
      char* bufr = psw + ((kb & 1) << 10);
      char* bufw = psw + (((kb & 1) ^ 1) << 10);
      // read P(kb) — in-order DS guarantees the buf was written
      const s16x8 pa =
          *(const s16x8*)(bufr + ((r16 * 64 + g * 16) ^ ((r16 & 7) << 4)));
      if (kb < 6) {  // write P(kb+1) into the other buffer (overlaps MFMA)
#pragma unroll
        for (int r = 0; r < 4; ++r) {
          const int prow = g * 4 + r;
          const int sw = (prow & 7) << 4;
          const float p0f = s[2 * kb + 2][r];
          const float p1f = (kb < 5) ? s[2 * kb + 3][r] : 0.f;
          *(short*)(bufw + ((prow * 64 + r16 * 2) ^ sw)) = f2bf(p0f);
          *(short*)(bufw + ((prow * 64 + (r16 + 16) * 2) ^ sw)) = f2bf(p1f);
        }
      }
#pragma unroll
      for (int df = 0; df < 4; ++df) {
        const s16x8 vf = *(const s16x8*)(Vsm + (df * 16 + r16) * 232 + kb * 32 + g * 8);
        o[df] = mfma16(pa, vf, o[df]);
      }
    }
    float rinv[4];
#pragma unroll
    for (int r = 0; r < 4; ++r) rinv[r] = 1.f / sum[r];
#pragma unroll
    for (int df = 0; df < 4; ++df)
#pragma unroll
      for (int r = 0; r < 4; ++r) {
        const int qrow = q0 + g * 4 + r;
        if (qrow < 197)
          QKV[base + (long)qrow * 2304 + h * 64 + df * 16 + r16] =
              f2bf(o[df][r] * rinv[r]);
      }
  }
}

// ---------------------------------------------------------------------------
extern "C" void kernel_launch(void* const* d_in, const int* in_sizes, int n_in,
                              void* d_out, int out_size, void* d_ws, size_t ws_size,
                              hipStream_t stream) {
  (void)in_sizes; (void)n_in; (void)out_size; (void)ws_size;
  const float* x   = (const float*)d_in[0];
  const float* Wq  = (const float*)d_in[1];
  const float* bq  = (const float*)d_in[2];
  const float* Wk  = (const float*)d_in[3];
  const float* bk  = (const float*)d_in[4];
  const float* Wv  = (const float*)d_in[5];
  const float* bv  = (const float*)d_in[6];
  const float* Wp  = (const float*)d_in[7];
  const float* bp  = (const float*)d_in[8];
  const float* lq1 = (const float*)d_in[9];
  const float* lk1 = (const float*)d_in[10];
  const float* lq2 = (const float*)d_in[11];
  const float* lk2 = (const float*)d_in[12];
  const float* lambda_init = (const float*)d_in[14];

  // workspace layout (bytes, 256-aligned); total 159,655,168
  char* ws = (char*)d_ws;
  short* xb   = (short*)ws;                  // x bf16: 25216x768
  short* wqkv = (short*)(ws + 38731776);     // [Wq;Wk;Wv] bf16: 2304x768
  short* wpb  = (short*)(ws + 42270720);     // Wp' bf16: 768x768
  float* bqkv = (float*)(ws + 43450368);     // [bq;bk;bv] f32: 2304
  float* lvp  = (float*)(ws + 43459584);     // lv scalar
  short* qkv  = (short*)(ws + 43459840);     // QKV bf16: 25216x2304 (O aliases Q cols)

  cvt_f32_to_bf16<<<2048, 256, 0, stream>>>(x, xb, 19365888 / 8);
  cvt_f32_to_bf16<<<288, 256, 0, stream>>>(Wq, wqkv, 73728);
  cvt_f32_to_bf16<<<288, 256, 0, stream>>>(Wk, wqkv + 589824, 73728);
  cvt_f32_to_bf16<<<288, 256, 0, stream>>>(Wv, wqkv + 1179648, 73728);
  lv_kernel<<<1, 64, 0, stream>>>(lq1, lk1, lq2, lk2, lambda_init, lvp);
  cvt_wp_prime<<<288, 256, 0, stream>>>(Wp, lvp, wpb);  // after lv_kernel
  hipMemcpyAsync(bqkv,        bq, 768 * 4, hipMemcpyDeviceToDevice, stream);
  hipMemcpyAsync(bqkv + 768,  bk, 768 * 4, hipMemcpyDeviceToDevice, stream);
  hipMemcpyAsync(bqkv + 1536, bv, 768 * 4, hipMemcpyDeviceToDevice, stream);

  // GEMM1: QKV = xb(25216x768) @ wqkv^T(2304x768), K=12*64
  gemm_bt<1, 12><<<197 * 18, 256, 0, stream>>>(xb, 768, wqkv, bqkv, qkv,
                                               25216, 2304);
  attn_kernel<<<128 * 12, 1024, 0, stream>>>(qkv);
  // GEMM2: out = attnO(25216x768, lda=2304) @ Wp'^T(768x768) + bp, K=12*64
  gemm_bt<0, 12><<<197 * 6, 256, 0, stream>>>(qkv, 2304, wpb, bp, d_out,
                                              25216, 768);
}

// Round 10
// 235.123 us; speedup vs baseline: 1.5359x; 1.0311x over previous
//
#include <hip/hip_runtime.h>
#include <hip/hip_bf16.h>
#include <stdint.h>

// ---------------------------------------------------------------------------
// DifferentialBiomedCLIP: x(128,197,768) f32 -> QKV proj -> 12-head attn with
// differential combine -> output proj. bf16 MFMA (16x16x32), f32 accum.
// GEMM: 128x128 tile + T1 bijective XCD swizzle + NKT=12 full unroll
//       (786 TF measured round 9).
// Attn: 512-thr blocks (8 waves, 2 blocks/CU) share one K/V LDS copy;
//       per-wave double-buffered P bounce (round-8 proven, ~42 us).
// Combine folded into Wp' = [Wp1, Wp2 - lv*Wp1] at weight-cvt time.
// ---------------------------------------------------------------------------

typedef __attribute__((ext_vector_type(4))) float f32x4;
typedef __attribute__((ext_vector_type(8))) short s16x8;
typedef __attribute__((ext_vector_type(8))) __bf16 bf16x8;

typedef const __attribute__((address_space(1))) void* gptr_t;
typedef __attribute__((address_space(3))) void* lptr_t;

__device__ __forceinline__ f32x4 mfma16(s16x8 a, s16x8 b, f32x4 c) {
  return __builtin_amdgcn_mfma_f32_16x16x32_bf16(
      __builtin_bit_cast(bf16x8, a), __builtin_bit_cast(bf16x8, b), c, 0, 0, 0);
}

__device__ __forceinline__ short f2bf(float f) {  // RNE f32->bf16 bits
  unsigned u = __float_as_uint(f);
  u += 0x7fffu + ((u >> 16) & 1u);
  return (short)(u >> 16);
}
__device__ __forceinline__ float bf2f(short s) {
  return __uint_as_float(((unsigned)(unsigned short)s) << 16);
}

__device__ __forceinline__ void gload_lds16(const void* g, void* l) {
  // async global->LDS, 16B per lane; LDS dest = wave-uniform base + lane*16
  __builtin_amdgcn_global_load_lds((gptr_t)g, (lptr_t)l, 16, 0, 0);
}

// ---------------------------------------------------------------------------
__global__ void cvt_f32_to_bf16(const float* __restrict__ src,
                                short* __restrict__ dst, long n8) {
  long i = (long)blockIdx.x * blockDim.x + threadIdx.x;
  const long stride = (long)gridDim.x * blockDim.x;
  for (; i < n8; i += stride) {
    const float4 a = ((const float4*)src)[2 * i];
    const float4 b = ((const float4*)src)[2 * i + 1];
    s16x8 o;
    o[0] = f2bf(a.x); o[1] = f2bf(a.y); o[2] = f2bf(a.z); o[3] = f2bf(a.w);
    o[4] = f2bf(b.x); o[5] = f2bf(b.y); o[6] = f2bf(b.z); o[7] = f2bf(b.w);
    ((s16x8*)dst)[i] = o;
  }
}

// lv = mean_h(exp(min(lq1.lk1,5)) - exp(min(lq2.lk2,5))) + lambda_init
__global__ void lv_kernel(const float* __restrict__ lq1, const float* __restrict__ lk1,
                          const float* __restrict__ lq2, const float* __restrict__ lk2,
                          const float* __restrict__ lambda_init, float* __restrict__ out) {
  const int l = threadIdx.x;
  float v = 0.f;
  if (l < 6) {
    float d1 = 0.f, d2 = 0.f;
    for (int j = 0; j < 64; ++j) {
      d1 += lq1[l * 64 + j] * lk1[l * 64 + j];
      d2 += lq2[l * 64 + j] * lk2[l * 64 + j];
    }
    v = expf(fminf(d1, 5.f)) - expf(fminf(d2, 5.f));
  }
  v += __shfl_xor(v, 1, 64);
  v += __shfl_xor(v, 2, 64);
  v += __shfl_xor(v, 4, 64);
  if (l == 0) out[0] = v * (1.f / 6.f) + lambda_init[0];
}

// Wp' (bf16): cols [0,384) = Wp, cols [384,768) = Wp[:,384:] - lv*Wp[:,:384].
__global__ void cvt_wp_prime(const float* __restrict__ Wp,
                             const float* __restrict__ lvp,
                             short* __restrict__ dst) {
  const int idx = blockIdx.x * blockDim.x + threadIdx.x;  // 73728 chunks of 8
  if (idx >= 73728) return;
  const float lv = *lvp;
  const int ic = idx % 96;  // col-chunk within a row (96 x 8 = 768)
  const float4 a = ((const float4*)Wp)[2 * idx];
  const float4 b = ((const float4*)Wp)[2 * idx + 1];
  float v[8] = {a.x, a.y, a.z, a.w, b.x, b.y, b.z, b.w};
  if (ic >= 48) {  // high half: subtract lv * (same row, col-384)
    const float4 a2 = ((const float4*)Wp)[2 * idx - 96];
    const float4 b2 = ((const float4*)Wp)[2 * idx - 95];
    v[0] -= lv * a2.x; v[1] -= lv * a2.y; v[2] -= lv * a2.z; v[3] -= lv * a2.w;
    v[4] -= lv * b2.x; v[5] -= lv * b2.y; v[6] -= lv * b2.z; v[7] -= lv * b2.w;
  }
  s16x8 o;
#pragma unroll
  for (int j = 0; j < 8; ++j) o[j] = f2bf(v[j]);
  ((s16x8*)dst)[idx] = o;
}

// ---------------------------------------------------------------------------
// C[M,N] = A[M,K] * B[N,K]^T + bias ; A row stride = lda (elements), B packed.
// 128x128 tile, BK=64, 4 waves, 16x16x32 bf16 MFMA, global_load_lds staging,
// XOR chunk swizzle, T1 bijective XCD swizzle. K = NKT*64 compile-time ->
// full unroll; per-iteration global offsets become 13-bit immediates.
template <int OUT_BF16, int NKT>
__global__ __launch_bounds__(256) void gemm_bt(const short* __restrict__ A, int lda,
                                               const short* __restrict__ B,
                                               const float* __restrict__ bias,
                                               void* __restrict__ C,
                                               int M, int N) {
  const int K = NKT * 64;
  const int nbx = N >> 7;
  // bijective XCD swizzle (m204 form, any grid size)
  const int nwg = gridDim.x;
  const int qq = nwg >> 3, rr = nwg & 7;
  const int xcd = blockIdx.x & 7, pos = blockIdx.x >> 3;
  const int wg = (xcd < rr ? xcd * (qq + 1) : rr * (qq + 1) + (xcd - rr) * qq) + pos;
  const int bx = wg % nbx;
  const int by = wg / nbx;
  const long m0 = (long)by << 7;
  const int n0 = bx << 7;
  __shared__ short Asm[128 * 64];
  __shared__ short Bsm[128 * 64];
  const int tid = threadIdx.x;
  const int lane = tid & 63;
  const int w = tid >> 6;
  const int wr = w >> 1, wc = w & 1;
  const int r16 = lane & 15, g = lane >> 4;

  // loop-invariant staging bases (per-thread); kt adds a constant immediate
  const short* abase[4];
  const short* bbase[4];
#pragma unroll
  for (int i = 0; i < 4; ++i) {
    const int c = i * 256 + tid;
    const int row = c >> 3;
    const int lc = (c & 7) ^ (row & 7);  // XOR chunk swizzle (involution)
    abase[i] = A + (m0 + row) * (long)lda + lc * 8;
    bbase[i] = B + (long)(n0 + row) * (long)K + lc * 8;
  }

  f32x4 acc[4][4];
#pragma unroll
  for (int i = 0; i < 4; ++i)
#pragma unroll
    for (int j = 0; j < 4; ++j) acc[i][j] = f32x4{0.f, 0.f, 0.f, 0.f};

#pragma unroll
  for (int kt = 0; kt < NKT; ++kt) {
    __syncthreads();  // all waves done reading LDS from previous step
#pragma unroll
    for (int i = 0; i < 4; ++i) {
      gload_lds16(abase[i] + kt * 64, Asm + i * 2048 + w * 512);
      gload_lds16(bbase[i] + kt * 64, Bsm + i * 2048 + w * 512);
    }
    asm volatile("s_waitcnt vmcnt(0)" ::: "memory");
    __syncthreads();
#pragma unroll
    for (int kk = 0; kk < 2; ++kk) {
      s16x8 av[4], bvv[4];
#pragma unroll
      for (int f = 0; f < 4; ++f) {
        const int ar = wr * 64 + f * 16 + r16;
        av[f] = *(const s16x8*)(Asm + ar * 64 + ((((kk << 2) + g) ^ (ar & 7)) << 3));
        const int br = wc * 64 + f * 16 + r16;
        bvv[f] = *(const s16x8*)(Bsm + br * 64 + ((((kk << 2) + g) ^ (br & 7)) << 3));
      }
#pragma unroll
      for (int fm = 0; fm < 4; ++fm)
#pragma unroll
        for (int fn = 0; fn < 4; ++fn)
          acc[fm][fn] = mfma16(av[fm], bvv[fn], acc[fm][fn]);
    }
  }
  // epilogue: D col=lane&15, row=(lane>>4)*4+reg
#pragma unroll
  for (int fm = 0; fm < 4; ++fm)
#pragma unroll
    for (int fn = 0; fn < 4; ++fn) {
      const int col = n0 + wc * 64 + fn * 16 + r16;
      const float bb = bias[col];
#pragma unroll
      for (int r = 0; r < 4; ++r) {
        const long row = m0 + wr * 64 + fm * 16 + g * 4 + r;
        const float v = acc[fm][fn][r] + bb;
        if (OUT_BF16) ((short*)C)[row * (long)N + col] = f2bf(v);
        else          ((float*)C)[row * (long)N + col] = v;
      }
    }
}

// ---------------------------------------------------------------------------
// Attention: one block per (b,h), 512 threads (8 waves) sharing ONE staged
// K/V LDS copy. QKV (25216 x 2304) bf16: cols [0,768)=Q, [768,1536)=K,
// [1536,2304)=V, head-major (h*64+d). Writes O in place over the Q columns
// (each wave reads its own Q rows before writing them).
// PV P-bounce is double-buffered: P(kb+1) writes overlap MFMA(kb); DS ops
// execute in-order per wave so no explicit wait between write(kb)/read(kb).
// LDS: K 29952 + V 29696 + P 16384 = 76032 B -> 2 blocks/CU = 16 waves/CU.
__global__ __launch_bounds__(512, 4) void attn_kernel(short* QKV) {
  const int b = blockIdx.x / 12;
  const int h = blockIdx.x % 12;
  __shared__ short Ksm[208 * 72];      // keys padded to 208, row stride 72
  __shared__ short Vsm[64 * 232];      // V transposed [d][key], stride 232
  __shared__ short Psm[8][2][512];     // per-wave DOUBLE-BUFFERED 16x32 P tile
  const int tid = threadIdx.x;
  const long base = (long)b * 197 * 2304;

  for (int c = tid; c < 208 * 8; c += 512) {  // stage K
    const int key = c >> 3, dch = c & 7;
    s16x8 val = {};
    if (key < 197)
      val = *(const s16x8*)(QKV + base + (long)key * 2304 + 768 + h * 64 + dch * 8);
    *(s16x8*)(Ksm + key * 72 + dch * 8) = val;
  }
  for (int c = tid; c < 224 * 8; c += 512) {  // stage V transposed (zero pad)
    const int key = c % 224, dch = c / 224;
    s16x8 val = {};
    if (key < 197)
      val = *(const s16x8*)(QKV + base + (long)key * 2304 + 1536 + h * 64 + dch * 8);
#pragma unroll
    for (int j = 0; j < 8; ++j) Vsm[(dch * 8 + j) * 232 + key] = val[j];
  }
  __syncthreads();

  const int lane = tid & 63, w = tid >> 6;  // w = 0..7
  const int r16 = lane & 15, g = lane >> 4;
  char* psw = (char*)Psm[w];

  for (int qt = w; qt < 13; qt += 8) {  // 13 q-tiles of 16 rows, 1-2 per wave
    const int q0 = qt * 16;
    int qr = q0 + r16;
    if (qr > 196) qr = 196;  // clamp; clamped rows computed but never stored
    const s16x8 qf0 = *(const s16x8*)(QKV + base + (long)qr * 2304 + h * 64 + g * 8);
    const s16x8 qf1 = *(const s16x8*)(QKV + base + (long)qr * 2304 + h * 64 + 32 + g * 8);

    f32x4 s[13];
#pragma unroll
    for (int kt = 0; kt < 13; ++kt) s[kt] = f32x4{0.f, 0.f, 0.f, 0.f};
#pragma unroll
    for (int kt = 0; kt < 13; ++kt) {
      const int krow = kt * 16 + r16;
      const s16x8 kf0 = *(const s16x8*)(Ksm + krow * 72 + g * 8);
      const s16x8 kf1 = *(const s16x8*)(Ksm + krow * 72 + 32 + g * 8);
      s[kt] = mfma16(qf0, kf0, s[kt]);
      s[kt] = mfma16(qf1, kf1, s[kt]);
    }
    // scale, mask pad keys, row max (rows at (lane>>4)*4+reg, key=lane&15)
    float mr[4] = {-1e30f, -1e30f, -1e30f, -1e30f};
#pragma unroll
    for (int kt = 0; kt < 13; ++kt)
#pragma unroll
      for (int r = 0; r < 4; ++r) {
        float sv = s[kt][r] * 0.125f;
        if (kt == 12 && r16 >= 5) sv = -1e30f;  // keys 197..207
        s[kt][r] = sv;
        mr[r] = fmaxf(mr[r], sv);
      }
#pragma unroll
    for (int r = 0; r < 4; ++r) {
      mr[r] = fmaxf(mr[r], __shfl_xor(mr[r], 1, 64));
      mr[r] = fmaxf(mr[r], __shfl_xor(mr[r], 2, 64));
      mr[r] = fmaxf(mr[r], __shfl_xor(mr[r], 4, 64));
      mr[r] = fmaxf(mr[r], __shfl_xor(mr[r], 8, 64));
    }
    float sum[4] = {0.f, 0.f, 0.f, 0.f};
#pragma unroll
    for (int kt = 0; kt < 13; ++kt)
#pragma unroll
      for (int r = 0; r < 4; ++r) {
        const float p = __expf(s[kt][r] - mr[r]);
        s[kt][r] = p;
        sum[r] += p;
      }
#pragma unroll
    for (int r = 0; r < 4; ++r) {
      sum[r] += __shfl_xor(sum[r], 1, 64);
      sum[r] += __shfl_xor(sum[r], 2, 64);
      sum[r] += __shfl_xor(sum[r], 4, 64);
      sum[r] += __shfl_xor(sum[r], 8, 64);
    }
    // PV with double-buffered P bounce.
    f32x4 o[4];
#pragma unroll
    for (int df = 0; df < 4; ++df) o[df] = f32x4{0.f, 0.f, 0.f, 0.f};
    // prologue: write P(kb=0) -> buf 0
#pragma unroll
    for (int r = 0; r < 4; ++r) {
      const int prow = g * 4 + r;
      const int sw = (prow & 7) << 4;
      *(short*)(psw + ((prow * 64 + r16 * 2) ^ sw)) = f2bf(s[0][r]);
      *(short*)(psw + ((prow * 64 + (r16 + 16) * 2) ^ sw)) = f2bf(s[1][r]);
    }
#pragma unroll
    for (int kb = 0; kb < 7; ++kb) {  // 7 blocks of 32 keys (last half-padded)
      char* bufr = psw + ((kb & 1) << 10);
      char* bufw = psw + (((kb & 1) ^ 1) << 10);
      // read P(kb) — in-order DS guarantees the buf was written
      const s16x8 pa =
          *(const s16x8*)(bufr + ((r16 * 64 + g * 16) ^ ((r16 & 7) << 4)));
      if (kb < 6) {  // write P(kb+1) into the other buffer (overlaps MFMA)
#pragma unroll
        for (int r = 0; r < 4; ++r) {
          const int prow = g * 4 + r;
          const int sw = (prow & 7) << 4;
          const float p0f = s[2 * kb + 2][r];
          const float p1f = (kb < 5) ? s[2 * kb + 3][r] : 0.f;
          *(short*)(bufw + ((prow * 64 + r16 * 2) ^ sw)) = f2bf(p0f);
          *(short*)(bufw + ((prow * 64 + (r16 + 16) * 2) ^ sw)) = f2bf(p1f);
        }
      }
#pragma unroll
      for (int df = 0; df < 4; ++df) {
        const s16x8 vf = *(const s16x8*)(Vsm + (df * 16 + r16) * 232 + kb * 32 + g * 8);
        o[df] = mfma16(pa, vf, o[df]);
      }
    }
    float rinv[4];
#pragma unroll
    for (int r = 0; r < 4; ++r) rinv[r] = 1.f / sum[r];
#pragma unroll
    for (int df = 0; df < 4; ++df)
#pragma unroll
      for (int r = 0; r < 4; ++r) {
        const int qrow = q0 + g * 4 + r;
        if (qrow < 197)
          QKV[base + (long)qrow * 2304 + h * 64 + df * 16 + r16] =
              f2bf(o[df][r] * rinv[r]);
      }
  }
}

// ---------------------------------------------------------------------------
extern "C" void kernel_launch(void* const* d_in, const int* in_sizes, int n_in,
                              void* d_out, int out_size, void* d_ws, size_t ws_size,
                              hipStream_t stream) {
  (void)in_sizes; (void)n_in; (void)out_size; (void)ws_size;
  const float* x   = (const float*)d_in[0];
  const float* Wq  = (const float*)d_in[1];
  const float* bq  = (const float*)d_in[2];
  const float* Wk  = (const float*)d_in[3];
  const float* bk  = (const float*)d_in[4];
  const float* Wv  = (const float*)d_in[5];
  const float* bv  = (const float*)d_in[6];
  const float* Wp  = (const float*)d_in[7];
  const float* bp  = (const float*)d_in[8];
  const float* lq1 = (const float*)d_in[9];
  const float* lk1 = (const float*)d_in[10];
  const float* lq2 = (const float*)d_in[11];
  const float* lk2 = (const float*)d_in[12];
  const float* lambda_init = (const float*)d_in[14];

  // workspace layout (bytes, 256-aligned); total 159,655,168
  char* ws = (char*)d_ws;
  short* xb   = (short*)ws;                  // x bf16: 25216x768
  short* wqkv = (short*)(ws + 38731776);     // [Wq;Wk;Wv] bf16: 2304x768
  short* wpb  = (short*)(ws + 42270720);     // Wp' bf16: 768x768
  float* bqkv = (float*)(ws + 43450368);     // [bq;bk;bv] f32: 2304
  float* lvp  = (float*)(ws + 43459584);     // lv scalar
  short* qkv  = (short*)(ws + 43459840);     // QKV bf16: 25216x2304 (O aliases Q cols)

  cvt_f32_to_bf16<<<2048, 256, 0, stream>>>(x, xb, 19365888 / 8);
  cvt_f32_to_bf16<<<288, 256, 0, stream>>>(Wq, wqkv, 73728);
  cvt_f32_to_bf16<<<288, 256, 0, stream>>>(Wk, wqkv + 589824, 73728);
  cvt_f32_to_bf16<<<288, 256, 0, stream>>>(Wv, wqkv + 1179648, 73728);
  lv_kernel<<<1, 64, 0, stream>>>(lq1, lk1, lq2, lk2, lambda_init, lvp);
  cvt_wp_prime<<<288, 256, 0, stream>>>(Wp, lvp, wpb);  // after lv_kernel
  hipMemcpyAsync(bqkv,        bq, 768 * 4, hipMemcpyDeviceToDevice, stream);
  hipMemcpyAsync(bqkv + 768,  bk, 768 * 4, hipMemcpyDeviceToDevice, stream);
  hipMemcpyAsync(bqkv + 1536, bv, 768 * 4, hipMemcpyDeviceToDevice, stream);

  // GEMM1: QKV = xb(25216x768) @ wqkv^T(2304x768), K=12*64
  gemm_bt<1, 12><<<197 * 18, 256, 0, stream>>>(xb, 768, wqkv, bqkv, qkv,
                                               25216, 2304);
  attn_kernel<<<128 * 12, 512, 0, stream>>>(qkv);
  // GEMM2: out = attnO(25216x768, lda=2304) @ Wp'^T(768x768) + bp, K=12*64
  gemm_bt<0, 12><<<197 * 6, 256, 0, stream>>>(qkv, 2304, wpb, bp, d_out,
                                              25216, 768);
}

// Round 11
// 218.388 us; speedup vs baseline: 1.6536x; 1.0766x over previous
//
#include <hip/hip_runtime.h>
#include <hip/hip_bf16.h>
#include <stdint.h>

// ---------------------------------------------------------------------------
// DifferentialBiomedCLIP: x(128,197,768) f32 -> QKV proj -> 12-head attn with
// differential combine -> output proj. bf16 MFMA (16x16x32), f32 accum.
// GEMM: 128x128 tile + T1 bijective XCD swizzle + NKT=12 full unroll (786 TF).
// Attn: 512-thr blocks (8 waves, 2 blocks/CU), K staged via global_load_lds
//       (XOR swizzle), V transposed in LDS, Q hoisted, P-bounce dbuf.
// Combine folded into Wp' = [Wp1, Wp2 - lv*Wp1]; prep ops fused to 1 kernel.
// ---------------------------------------------------------------------------

typedef __attribute__((ext_vector_type(4))) float f32x4;
typedef __attribute__((ext_vector_type(8))) short s16x8;
typedef __attribute__((ext_vector_type(8))) __bf16 bf16x8;

typedef const __attribute__((address_space(1))) void* gptr_t;
typedef __attribute__((address_space(3))) void* lptr_t;

__device__ __forceinline__ f32x4 mfma16(s16x8 a, s16x8 b, f32x4 c) {
  return __builtin_amdgcn_mfma_f32_16x16x32_bf16(
      __builtin_bit_cast(bf16x8, a), __builtin_bit_cast(bf16x8, b), c, 0, 0, 0);
}

__device__ __forceinline__ short f2bf(float f) {  // RNE f32->bf16 bits
  unsigned u = __float_as_uint(f);
  u += 0x7fffu + ((u >> 16) & 1u);
  return (short)(u >> 16);
}
__device__ __forceinline__ float bf2f(short s) {
  return __uint_as_float(((unsigned)(unsigned short)s) << 16);
}

__device__ __forceinline__ void gload_lds16(const void* g, void* l) {
  // async global->LDS, 16B per lane; LDS dest = wave-uniform base + lane*16
  __builtin_amdgcn_global_load_lds((gptr_t)g, (lptr_t)l, 16, 0, 0);
}

// ---------------------------------------------------------------------------
__global__ void cvt_f32_to_bf16(const float* __restrict__ src,
                                short* __restrict__ dst, long n8) {
  long i = (long)blockIdx.x * blockDim.x + threadIdx.x;
  const long stride = (long)gridDim.x * blockDim.x;
  for (; i < n8; i += stride) {
    const float4 a = ((const float4*)src)[2 * i];
    const float4 b = ((const float4*)src)[2 * i + 1];
    s16x8 o;
    o[0] = f2bf(a.x); o[1] = f2bf(a.y); o[2] = f2bf(a.z); o[3] = f2bf(a.w);
    o[4] = f2bf(b.x); o[5] = f2bf(b.y); o[6] = f2bf(b.z); o[7] = f2bf(b.w);
    ((s16x8*)dst)[i] = o;
  }
}

// One launch: Wq/Wk/Wv f32->bf16 into wqkv (blocks 0..863), bias pack
// (block 864), lv scalar (block 865).
__global__ void prep_kernel(const float* __restrict__ Wq, const float* __restrict__ Wk,
                            const float* __restrict__ Wv, const float* __restrict__ bq,
                            const float* __restrict__ bk, const float* __restrict__ bv,
                            const float* __restrict__ lq1, const float* __restrict__ lk1,
                            const float* __restrict__ lq2, const float* __restrict__ lk2,
                            const float* __restrict__ lambda_init,
                            short* __restrict__ wqkv, float* __restrict__ bqkv,
                            float* __restrict__ lvp) {
  const int blk = blockIdx.x;
  if (blk < 864) {
    const int which = blk / 288;
    const int idx = (blk - which * 288) * 256 + threadIdx.x;  // [0, 73728)
    const float* src = (which == 0) ? Wq : (which == 1) ? Wk : Wv;
    const float4 a = ((const float4*)src)[2 * idx];
    const float4 b = ((const float4*)src)[2 * idx + 1];
    s16x8 o;
    o[0] = f2bf(a.x); o[1] = f2bf(a.y); o[2] = f2bf(a.z); o[3] = f2bf(a.w);
    o[4] = f2bf(b.x); o[5] = f2bf(b.y); o[6] = f2bf(b.z); o[7] = f2bf(b.w);
    ((s16x8*)(wqkv + which * 589824))[idx] = o;
  } else if (blk == 864) {  // pack [bq;bk;bv] into bqkv (576 float4)
    for (int j = threadIdx.x; j < 576; j += 256) {
      float4 v;
      if (j < 192)      v = ((const float4*)bq)[j];
      else if (j < 384) v = ((const float4*)bk)[j - 192];
      else              v = ((const float4*)bv)[j - 384];
      ((float4*)bqkv)[j] = v;
    }
  } else {  // lv = mean_h(exp(min(lq1.lk1,5)) - exp(min(lq2.lk2,5))) + lambda
    const int l = threadIdx.x;
    if (l < 64) {
      float v = 0.f;
      if (l < 6) {
        float d1 = 0.f, d2 = 0.f;
        for (int j = 0; j < 64; ++j) {
          d1 += lq1[l * 64 + j] * lk1[l * 64 + j];
          d2 += lq2[l * 64 + j] * lk2[l * 64 + j];
        }
        v = expf(fminf(d1, 5.f)) - expf(fminf(d2, 5.f));
      }
      v += __shfl_xor(v, 1, 64);
      v += __shfl_xor(v, 2, 64);
      v += __shfl_xor(v, 4, 64);
      if (l == 0) lvp[0] = v * (1.f / 6.f) + lambda_init[0];
    }
  }
}

// Wp' (bf16): cols [0,384) = Wp, cols [384,768) = Wp[:,384:] - lv*Wp[:,:384].
__global__ void cvt_wp_prime(const float* __restrict__ Wp,
                             const float* __restrict__ lvp,
                             short* __restrict__ dst) {
  const int idx = blockIdx.x * blockDim.x + threadIdx.x;  // 73728 chunks of 8
  if (idx >= 73728) return;
  const float lv = *lvp;
  const int ic = idx % 96;  // col-chunk within a row (96 x 8 = 768)
  const float4 a = ((const float4*)Wp)[2 * idx];
  const float4 b = ((const float4*)Wp)[2 * idx + 1];
  float v[8] = {a.x, a.y, a.z, a.w, b.x, b.y, b.z, b.w};
  if (ic >= 48) {  // high half: subtract lv * (same row, col-384)
    const float4 a2 = ((const float4*)Wp)[2 * idx - 96];
    const float4 b2 = ((const float4*)Wp)[2 * idx - 95];
    v[0] -= lv * a2.x; v[1] -= lv * a2.y; v[2] -= lv * a2.z; v[3] -= lv * a2.w;
    v[4] -= lv * b2.x; v[5] -= lv * b2.y; v[6] -= lv * b2.z; v[7] -= lv * b2.w;
  }
  s16x8 o;
#pragma unroll
  for (int j = 0; j < 8; ++j) o[j] = f2bf(v[j]);
  ((s16x8*)dst)[idx] = o;
}

// ---------------------------------------------------------------------------
// C[M,N] = A[M,K] * B[N,K]^T + bias ; A row stride = lda (elements), B packed.
// 128x128 tile, BK=64, 4 waves, 16x16x32 bf16 MFMA, global_load_lds staging,
// XOR chunk swizzle, T1 bijective XCD swizzle. K = NKT*64 compile-time ->
// full unroll; per-iteration global offsets become 13-bit immediates.
template <int OUT_BF16, int NKT>
__global__ __launch_bounds__(256) void gemm_bt(const short* __restrict__ A, int lda,
                                               const short* __restrict__ B,
                                               const float* __restrict__ bias,
                                               void* __restrict__ C,
                                               int M, int N) {
  const int K = NKT * 64;
  const int nbx = N >> 7;
  // bijective XCD swizzle (m204 form, any grid size)
  const int nwg = gridDim.x;
  const int qq = nwg >> 3, rr = nwg & 7;
  const int xcd = blockIdx.x & 7, pos = blockIdx.x >> 3;
  const int wg = (xcd < rr ? xcd * (qq + 1) : rr * (qq + 1) + (xcd - rr) * qq) + pos;
  const int bx = wg % nbx;
  const int by = wg / nbx;
  const long m0 = (long)by << 7;
  const int n0 = bx << 7;
  __shared__ short Asm[128 * 64];
  __shared__ short Bsm[128 * 64];
  const int tid = threadIdx.x;
  const int lane = tid & 63;
  const int w = tid >> 6;
  const int wr = w >> 1, wc = w & 1;
  const int r16 = lane & 15, g = lane >> 4;

  // loop-invariant staging bases (per-thread); kt adds a constant immediate
  const short* abase[4];
  const short* bbase[4];
#pragma unroll
  for (int i = 0; i < 4; ++i) {
    const int c = i * 256 + tid;
    const int row = c >> 3;
    const int lc = (c & 7) ^ (row & 7);  // XOR chunk swizzle (involution)
    abase[i] = A + (m0 + row) * (long)lda + lc * 8;
    bbase[i] = B + (long)(n0 + row) * (long)K + lc * 8;
  }

  f32x4 acc[4][4];
#pragma unroll
  for (int i = 0; i < 4; ++i)
#pragma unroll
    for (int j = 0; j < 4; ++j) acc[i][j] = f32x4{0.f, 0.f, 0.f, 0.f};

#pragma unroll
  for (int kt = 0; kt < NKT; ++kt) {
    __syncthreads();  // all waves done reading LDS from previous step
#pragma unroll
    for (int i = 0; i < 4; ++i) {
      gload_lds16(abase[i] + kt * 64, Asm + i * 2048 + w * 512);
      gload_lds16(bbase[i] + kt * 64, Bsm + i * 2048 + w * 512);
    }
    asm volatile("s_waitcnt vmcnt(0)" ::: "memory");
    __syncthreads();
#pragma unroll
    for (int kk = 0; kk < 2; ++kk) {
      s16x8 av[4], bvv[4];
#pragma unroll
      for (int f = 0; f < 4; ++f) {
        const int ar = wr * 64 + f * 16 + r16;
        av[f] = *(const s16x8*)(Asm + ar * 64 + ((((kk << 2) + g) ^ (ar & 7)) << 3));
        const int br = wc * 64 + f * 16 + r16;
        bvv[f] = *(const s16x8*)(Bsm + br * 64 + ((((kk << 2) + g) ^ (br & 7)) << 3));
      }
#pragma unroll
      for (int fm = 0; fm < 4; ++fm)
#pragma unroll
        for (int fn = 0; fn < 4; ++fn)
          acc[fm][fn] = mfma16(av[fm], bvv[fn], acc[fm][fn]);
    }
  }
  // epilogue: D col=lane&15, row=(lane>>4)*4+reg
#pragma unroll
  for (int fm = 0; fm < 4; ++fm)
#pragma unroll
    for (int fn = 0; fn < 4; ++fn) {
      const int col = n0 + wc * 64 + fn * 16 + r16;
      const float bb = bias[col];
#pragma unroll
      for (int r = 0; r < 4; ++r) {
        const long row = m0 + wr * 64 + fm * 16 + g * 4 + r;
        const float v = acc[fm][fn][r] + bb;
        if (OUT_BF16) ((short*)C)[row * (long)N + col] = f2bf(v);
        else          ((float*)C)[row * (long)N + col] = v;
      }
    }
}

// ---------------------------------------------------------------------------
// Attention: one block per (b,h), 512 threads (8 waves) sharing ONE staged
// K/V LDS copy. QKV (25216 x 2304) bf16: cols [0,768)=Q, [768,1536)=K,
// [1536,2304)=V, head-major (h*64+d). Writes O in place over the Q columns
// (each wave reads its own Q rows -- hoisted to kernel entry -- before any
// wave writes them; rows are wave-private).
// K staged via global_load_lds into linear [208][64] with XOR chunk swizzle
// (pre-swizzled source + swizzled read; rows 197..207 zero-filled by ds_write).
// V staged transposed [d][key]. PV P-bounce double-buffered (DS in-order).
// LDS: K 26624 + V 29696 + P 16384 = 72704 B -> 2 blocks/CU = 16 waves/CU.
__global__ __launch_bounds__(512, 4) void attn_kernel(short* QKV) {
  const int b = blockIdx.x / 12;
  const int h = blockIdx.x % 12;
  __shared__ short Ksm[208 * 64];      // linear, XOR-swizzled columns
  __shared__ short Vsm[64 * 232];      // V transposed [d][key], stride 232
  __shared__ short Psm[8][2][512];     // per-wave double-buffered 16x32 P tile
  const int tid = threadIdx.x;
  const long base = (long)b * 197 * 2304;
  const int lane = tid & 63, w = tid >> 6;  // w = 0..7
  const int r16 = lane & 15, g = lane >> 4;

  // hoist Q fragments for both q-tiles (qt = w and w+8) -- hides HBM latency
  // under staging; safe: these rows are written only by this wave, later.
  int qra = w * 16 + r16;            // qt = w (always < 13)
  const s16x8 qa0 = *(const s16x8*)(QKV + base + (long)qra * 2304 + h * 64 + g * 8);
  const s16x8 qa1 = *(const s16x8*)(QKV + base + (long)qra * 2304 + h * 64 + 32 + g * 8);
  s16x8 qb0 = {}, qb1 = {};
  if (w < 5) {                       // qt = w+8 exists (w+8 < 13)
    int qrb = (w + 8) * 16 + r16;
    if (qrb > 196) qrb = 196;        // clamp; computed but never stored
    qb0 = *(const s16x8*)(QKV + base + (long)qrb * 2304 + h * 64 + g * 8);
    qb1 = *(const s16x8*)(QKV + base + (long)qrb * 2304 + h * 64 + 32 + g * 8);
  }

  // stage K via async global_load_lds: 197 rows x 8 chunks, linear LDS dest,
  // pre-swizzled global source (rule #21)
  for (int c = tid; c < 1576; c += 512) {
    const int row = c >> 3;
    const int lc = (c & 7) ^ (row & 7);
    gload_lds16(QKV + base + (long)row * 2304 + 768 + h * 64 + lc * 8,
                Ksm + (c & ~63) * 8 /* wave-uniform base */ + (c & 63) * 8);
  }
  for (int c = tid; c < 88; c += 512)  // zero rows 197..207 (88 chunks)
    *(s16x8*)(Ksm + 197 * 64 + c * 8) = s16x8{};

  for (int c = tid; c < 224 * 8; c += 512) {  // stage V transposed (zero pad)
    const int key = c % 224, dch = c / 224;
    s16x8 val = {};
    if (key < 197)
      val = *(const s16x8*)(QKV + base + (long)key * 2304 + 1536 + h * 64 + dch * 8);
#pragma unroll
    for (int j = 0; j < 8; ++j) Vsm[(dch * 8 + j) * 232 + key] = val[j];
  }
  asm volatile("s_waitcnt vmcnt(0)" ::: "memory");
  __syncthreads();

  char* psw = (char*)Psm[w];

  for (int qt = w; qt < 13; qt += 8) {  // 13 q-tiles of 16 rows, 1-2 per wave
    const int q0 = qt * 16;
    const s16x8 qf0 = (qt == w) ? qa0 : qb0;
    const s16x8 qf1 = (qt == w) ? qa1 : qb1;

    f32x4 s[13];
#pragma unroll
    for (int kt = 0; kt < 13; ++kt) s[kt] = f32x4{0.f, 0.f, 0.f, 0.f};
#pragma unroll
    for (int kt = 0; kt < 13; ++kt) {
      const int krow = kt * 16 + r16;
      const int sw = krow & 7;
      const s16x8 kf0 = *(const s16x8*)(Ksm + krow * 64 + ((g ^ sw) << 3));
      const s16x8 kf1 = *(const s16x8*)(Ksm + krow * 64 + (((g + 4) ^ sw) << 3));
      s[kt] = mfma16(qf0, kf0, s[kt]);
      s[kt] = mfma16(qf1, kf1, s[kt]);
    }
    // scale, mask pad keys, row max (rows at (lane>>4)*4+reg, key=lane&15)
    float mr[4] = {-1e30f, -1e30f, -1e30f, -1e30f};
#pragma unroll
    for (int kt = 0; kt < 13; ++kt)
#pragma unroll
      for (int r = 0; r < 4; ++r) {
        float sv = s[kt][r] * 0.125f;
        if (kt == 12 && r16 >= 5) sv = -1e30f;  // keys 197..207
        s[kt][r] = sv;
        mr[r] = fmaxf(mr[r], sv);
      }
#pragma unroll
    for (int r = 0; r < 4; ++r) {
      mr[r] = fmaxf(mr[r], __shfl_xor(mr[r], 1, 64));
      mr[r] = fmaxf(mr[r], __shfl_xor(mr[r], 2, 64));
      mr[r] = fmaxf(mr[r], __shfl_xor(mr[r], 4, 64));
      mr[r] = fmaxf(mr[r], __shfl_xor(mr[r], 8, 64));
    }
    float sum[4] = {0.f, 0.f, 0.f, 0.f};
#pragma unroll
    for (int kt = 0; kt < 13; ++kt)
#pragma unroll
      for (int r = 0; r < 4; ++r) {
        const float p = __expf(s[kt][r] - mr[r]);
        s[kt][r] = p;
        sum[r] += p;
      }
#pragma unroll
    for (int r = 0; r < 4; ++r) {
      sum[r] += __shfl_xor(sum[r], 1, 64);
      sum[r] += __shfl_xor(sum[r], 2, 64);
      sum[r] += __shfl_xor(sum[r], 4, 64);
      sum[r] += __shfl_xor(sum[r], 8, 64);
    }
    // PV with double-buffered P bounce.
    f32x4 o[4];
#pragma unroll
    for (int df = 0; df < 4; ++df) o[df] = f32x4{0.f, 0.f, 0.f, 0.f};
    // prologue: write P(kb=0) -> buf 0
#pragma unroll
    for (int r = 0; r < 4; ++r) {
      const int prow = g * 4 + r;
      const int sw = (prow & 7) << 4;
      *(short*)(psw + ((prow * 64 + r16 * 2) ^ sw)) = f2bf(s[0][r]);
      *(short*)(psw + ((prow * 64 + (r16 + 16) * 2) ^ sw)) = f2bf(s[1][r]);
    }
#pragma unroll
    for (int kb = 0; kb < 7; ++kb) {  // 7 blocks of 32 keys (last half-padded)
      char* bufr = psw + ((kb & 1) << 10);
      char* bufw = psw + (((kb & 1) ^ 1) << 10);
      // read P(kb) -- in-order DS guarantees the buf was written
      const s16x8 pa =
          *(const s16x8*)(bufr + ((r16 * 64 + g * 16) ^ ((r16 & 7) << 4)));
      if (kb < 6) {  // write P(kb+1) into the other buffer (overlaps MFMA)
#pragma unroll
        for (int r = 0; r < 4; ++r) {
          const int prow = g * 4 + r;
          const int sw = (prow & 7) << 4;
          const float p0f = s[2 * kb + 2][r];
          const float p1f = (kb < 5) ? s[2 * kb + 3][r] : 0.f;
          *(short*)(bufw + ((prow * 64 + r16 * 2) ^ sw)) = f2bf(p0f);
          *(short*)(bufw + ((prow * 64 + (r16 + 16) * 2) ^ sw)) = f2bf(p1f);
        }
      }
#pragma unroll
      for (int df = 0; df < 4; ++df) {
        const s16x8 vf = *(const s16x8*)(Vsm + (df * 16 + r16) * 232 + kb * 32 + g * 8);
        o[df] = mfma16(pa, vf, o[df]);
      }
    }
    float rinv[4];
#pragma unroll
    for (int r = 0; r < 4; ++r) rinv[r] = 1.f / sum[r];
#pragma unroll
    for (int df = 0; df < 4; ++df)
#pragma unroll
      for (int r = 0; r < 4; ++r) {
        const int qrow = q0 + g * 4 + r;
        if (qrow < 197)
          QKV[base + (long)qrow * 2304 + h * 64 + df * 16 + r16] =
              f2bf(o[df][r] * rinv[r]);
      }
  }
}

// ---------------------------------------------------------------------------
extern "C" void kernel_launch(void* const* d_in, const int* in_sizes, int n_in,
                              void* d_out, int out_size, void* d_ws, size_t ws_size,
                              hipStream_t stream) {
  (void)in_sizes; (void)n_in; (void)out_size; (void)ws_size;
  const float* x   = (const float*)d_in[0];
  const float* Wq  = (const float*)d_in[1];
  const float* bq  = (const float*)d_in[2];
  const float* Wk  = (const float*)d_in[3];
  const float* bk  = (const float*)d_in[4];
  const float* Wv  = (const float*)d_in[5];
  const float* bv  = (const float*)d_in[6];
  const float* Wp  = (const float*)d_in[7];
  const float* bp  = (const float*)d_in[8];
  const float* lq1 = (const float*)d_in[9];
  const float* lk1 = (const float*)d_in[10];
  const float* lq2 = (const float*)d_in[11];
  const float* lk2 = (const float*)d_in[12];
  const float* lambda_init = (const float*)d_in[14];

  // workspace layout (bytes, 256-aligned); total 159,655,168
  char* ws = (char*)d_ws;
  short* xb   = (short*)ws;                  // x bf16: 25216x768
  short* wqkv = (short*)(ws + 38731776);     // [Wq;Wk;Wv] bf16: 2304x768
  short* wpb  = (short*)(ws + 42270720);     // Wp' bf16: 768x768
  float* bqkv = (float*)(ws + 43450368);     // [bq;bk;bv] f32: 2304
  float* lvp  = (float*)(ws + 43459584);     // lv scalar
  short* qkv  = (short*)(ws + 43459840);     // QKV bf16: 25216x2304 (O aliases Q cols)

  cvt_f32_to_bf16<<<2048, 256, 0, stream>>>(x, xb, 19365888 / 8);
  prep_kernel<<<866, 256, 0, stream>>>(Wq, Wk, Wv, bq, bk, bv,
                                       lq1, lk1, lq2, lk2, lambda_init,
                                       wqkv, bqkv, lvp);
  cvt_wp_prime<<<288, 256, 0, stream>>>(Wp, lvp, wpb);  // after prep (lv dep)

  // GEMM1: QKV = xb(25216x768) @ wqkv^T(2304x768), K=12*64
  gemm_bt<1, 12><<<197 * 18, 256, 0, stream>>>(xb, 768, wqkv, bqkv, qkv,
                                               25216, 2304);
  attn_kernel<<<128 * 12, 512, 0, stream>>>(qkv);
  // GEMM2: out = attnO(25216x768, lda=2304) @ Wp'^T(768x768) + bp, K=12*64
  gemm_bt<0, 12><<<197 * 6, 256, 0, stream>>>(qkv, 2304, wpb, bp, d_out,
                                              25216, 768);
}

// Round 12
// 214.701 us; speedup vs baseline: 1.6820x; 1.0172x over previous
//
#include <hip/hip_runtime.h>
#include <hip/hip_bf16.h>
#include <stdint.h>

// ---------------------------------------------------------------------------
// DifferentialBiomedCLIP: x(128,197,768) f32 -> QKV proj -> 12-head attn with
// differential combine -> output proj. bf16 MFMA (16x16x32), f32 accum.
// GEMM: 128x128 tile + T1 bijective XCD swizzle + NKT=12 full unroll (786 TF).
// Attn: 512-thr blocks (8 waves, 2 blocks/CU), K via global_load_lds (XOR
//       swizzle), V transposed in LDS, Q hoisted, P-bounce dbuf, T5 setprio.
// Combine folded into Wp' = [Wp1, Wp2 - lv*Wp1]; all prep fused to 1 kernel.
// ---------------------------------------------------------------------------

typedef __attribute__((ext_vector_type(4))) float f32x4;
typedef __attribute__((ext_vector_type(8))) short s16x8;
typedef __attribute__((ext_vector_type(8))) __bf16 bf16x8;

typedef const __attribute__((address_space(1))) void* gptr_t;
typedef __attribute__((address_space(3))) void* lptr_t;

__device__ __forceinline__ f32x4 mfma16(s16x8 a, s16x8 b, f32x4 c) {
  return __builtin_amdgcn_mfma_f32_16x16x32_bf16(
      __builtin_bit_cast(bf16x8, a), __builtin_bit_cast(bf16x8, b), c, 0, 0, 0);
}

__device__ __forceinline__ short f2bf(float f) {  // RNE f32->bf16 bits
  unsigned u = __float_as_uint(f);
  u += 0x7fffu + ((u >> 16) & 1u);
  return (short)(u >> 16);
}
__device__ __forceinline__ float bf2f(short s) {
  return __uint_as_float(((unsigned)(unsigned short)s) << 16);
}

__device__ __forceinline__ void gload_lds16(const void* g, void* l) {
  // async global->LDS, 16B per lane; LDS dest = wave-uniform base + lane*16
  __builtin_amdgcn_global_load_lds((gptr_t)g, (lptr_t)l, 16, 0, 0);
}

// ---------------------------------------------------------------------------
// One launch: x f32->bf16 (blocks 0..2047, grid-stride), Wq/Wk/Wv f32->bf16
// (blocks 2048..2911), bias pack (2912), lv scalar (2913).
__global__ void prep_kernel(const float* __restrict__ x,
                            const float* __restrict__ Wq, const float* __restrict__ Wk,
                            const float* __restrict__ Wv, const float* __restrict__ bq,
                            const float* __restrict__ bk, const float* __restrict__ bv,
                            const float* __restrict__ lq1, const float* __restrict__ lk1,
                            const float* __restrict__ lq2, const float* __restrict__ lk2,
                            const float* __restrict__ lambda_init,
                            short* __restrict__ xb,
                            short* __restrict__ wqkv, float* __restrict__ bqkv,
                            float* __restrict__ lvp) {
  const int blk = blockIdx.x;
  if (blk < 2048) {  // x: 19365888 floats = 2420736 chunks of 8
    const long n8 = 19365888 / 8;
    const long stride = 2048L * 256;
    for (long i = (long)blk * 256 + threadIdx.x; i < n8; i += stride) {
      const float4 a = ((const float4*)x)[2 * i];
      const float4 b = ((const float4*)x)[2 * i + 1];
      s16x8 o;
      o[0] = f2bf(a.x); o[1] = f2bf(a.y); o[2] = f2bf(a.z); o[3] = f2bf(a.w);
      o[4] = f2bf(b.x); o[5] = f2bf(b.y); o[6] = f2bf(b.z); o[7] = f2bf(b.w);
      ((s16x8*)xb)[i] = o;
    }
  } else if (blk < 2912) {  // weights: 3 x 288 blocks
    const int wb = blk - 2048;
    const int which = wb / 288;
    const int idx = (wb - which * 288) * 256 + threadIdx.x;  // [0, 73728)
    const float* src = (which == 0) ? Wq : (which == 1) ? Wk : Wv;
    const float4 a = ((const float4*)src)[2 * idx];
    const float4 b = ((const float4*)src)[2 * idx + 1];
    s16x8 o;
    o[0] = f2bf(a.x); o[1] = f2bf(a.y); o[2] = f2bf(a.z); o[3] = f2bf(a.w);
    o[4] = f2bf(b.x); o[5] = f2bf(b.y); o[6] = f2bf(b.z); o[7] = f2bf(b.w);
    ((s16x8*)(wqkv + which * 589824))[idx] = o;
  } else if (blk == 2912) {  // pack [bq;bk;bv] into bqkv (576 float4)
    for (int j = threadIdx.x; j < 576; j += 256) {
      float4 v;
      if (j < 192)      v = ((const float4*)bq)[j];
      else if (j < 384) v = ((const float4*)bk)[j - 192];
      else              v = ((const float4*)bv)[j - 384];
      ((float4*)bqkv)[j] = v;
    }
  } else {  // lv = mean_h(exp(min(lq1.lk1,5)) - exp(min(lq2.lk2,5))) + lambda
    const int l = threadIdx.x;
    if (l < 64) {
      float v = 0.f;
      if (l < 6) {
        float d1 = 0.f, d2 = 0.f;
        for (int j = 0; j < 64; ++j) {
          d1 += lq1[l * 64 + j] * lk1[l * 64 + j];
          d2 += lq2[l * 64 + j] * lk2[l * 64 + j];
        }
        v = expf(fminf(d1, 5.f)) - expf(fminf(d2, 5.f));
      }
      v += __shfl_xor(v, 1, 64);
      v += __shfl_xor(v, 2, 64);
      v += __shfl_xor(v, 4, 64);
      if (l == 0) lvp[0] = v * (1.f / 6.f) + lambda_init[0];
    }
  }
}

// Wp' (bf16): cols [0,384) = Wp, cols [384,768) = Wp[:,384:] - lv*Wp[:,:384].
__global__ void cvt_wp_prime(const float* __restrict__ Wp,
                             const float* __restrict__ lvp,
                             short* __restrict__ dst) {
  const int idx = blockIdx.x * blockDim.x + threadIdx.x;  // 73728 chunks of 8
  if (idx >= 73728) return;
  const float lv = *lvp;
  const int ic = idx % 96;  // col-chunk within a row (96 x 8 = 768)
  const float4 a = ((const float4*)Wp)[2 * idx];
  const float4 b = ((const float4*)Wp)[2 * idx + 1];
  float v[8] = {a.x, a.y, a.z, a.w, b.x, b.y, b.z, b.w};
  if (ic >= 48) {  // high half: subtract lv * (same row, col-384)
    const float4 a2 = ((const float4*)Wp)[2 * idx - 96];
    const float4 b2 = ((const float4*)Wp)[2 * idx - 95];
    v[0] -= lv * a2.x; v[1] -= lv * a2.y; v[2] -= lv * a2.z; v[3] -= lv * a2.w;
    v[4] -= lv * b2.x; v[5] -= lv * b2.y; v[6] -= lv * b2.z; v[7] -= lv * b2.w;
  }
  s16x8 o;
#pragma unroll
  for (int j = 0; j < 8; ++j) o[j] = f2bf(v[j]);
  ((s16x8*)dst)[idx] = o;
}

// ---------------------------------------------------------------------------
// C[M,N] = A[M,K] * B[N,K]^T + bias ; A row stride = lda (elements), B packed.
// 128x128 tile, BK=64, 4 waves, 16x16x32 bf16 MFMA, global_load_lds staging,
// XOR chunk swizzle, T1 bijective XCD swizzle. K = NKT*64 compile-time ->
// full unroll; per-iteration global offsets become 13-bit immediates.
template <int OUT_BF16, int NKT>
__global__ __launch_bounds__(256) void gemm_bt(const short* __restrict__ A, int lda,
                                               const short* __restrict__ B,
                                               const float* __restrict__ bias,
                                               void* __restrict__ C,
                                               int M, int N) {
  const int K = NKT * 64;
  const int nbx = N >> 7;
  // bijective XCD swizzle (m204 form, any grid size)
  const int nwg = gridDim.x;
  const int qq = nwg >> 3, rr = nwg & 7;
  const int xcd = blockIdx.x & 7, pos = blockIdx.x >> 3;
  const int wg = (xcd < rr ? xcd * (qq + 1) : rr * (qq + 1) + (xcd - rr) * qq) + pos;
  const int bx = wg % nbx;
  const int by = wg / nbx;
  const long m0 = (long)by << 7;
  const int n0 = bx << 7;
  __shared__ short Asm[128 * 64];
  __shared__ short Bsm[128 * 64];
  const int tid = threadIdx.x;
  const int lane = tid & 63;
  const int w = tid >> 6;
  const int wr = w >> 1, wc = w & 1;
  const int r16 = lane & 15, g = lane >> 4;

  // loop-invariant staging bases (per-thread); kt adds a constant immediate
  const short* abase[4];
  const short* bbase[4];
#pragma unroll
  for (int i = 0; i < 4; ++i) {
    const int c = i * 256 + tid;
    const int row = c >> 3;
    const int lc = (c & 7) ^ (row & 7);  // XOR chunk swizzle (involution)
    abase[i] = A + (m0 + row) * (long)lda + lc * 8;
    bbase[i] = B + (long)(n0 + row) * (long)K + lc * 8;
  }

  f32x4 acc[4][4];
#pragma unroll
  for (int i = 0; i < 4; ++i)
#pragma unroll
    for (int j = 0; j < 4; ++j) acc[i][j] = f32x4{0.f, 0.f, 0.f, 0.f};

#pragma unroll
  for (int kt = 0; kt < NKT; ++kt) {
    __syncthreads();  // all waves done reading LDS from previous step
#pragma unroll
    for (int i = 0; i < 4; ++i) {
      gload_lds16(abase[i] + kt * 64, Asm + i * 2048 + w * 512);
      gload_lds16(bbase[i] + kt * 64, Bsm + i * 2048 + w * 512);
    }
    asm volatile("s_waitcnt vmcnt(0)" ::: "memory");
    __syncthreads();
#pragma unroll
    for (int kk = 0; kk < 2; ++kk) {
      s16x8 av[4], bvv[4];
#pragma unroll
      for (int f = 0; f < 4; ++f) {
        const int ar = wr * 64 + f * 16 + r16;
        av[f] = *(const s16x8*)(Asm + ar * 64 + ((((kk << 2) + g) ^ (ar & 7)) << 3));
        const int br = wc * 64 + f * 16 + r16;
        bvv[f] = *(const s16x8*)(Bsm + br * 64 + ((((kk << 2) + g) ^ (br & 7)) << 3));
      }
#pragma unroll
      for (int fm = 0; fm < 4; ++fm)
#pragma unroll
        for (int fn = 0; fn < 4; ++fn)
          acc[fm][fn] = mfma16(av[fm], bvv[fn], acc[fm][fn]);
    }
  }
  // epilogue: D col=lane&15, row=(lane>>4)*4+reg
#pragma unroll
  for (int fm = 0; fm < 4; ++fm)
#pragma unroll
    for (int fn = 0; fn < 4; ++fn) {
      const int col = n0 + wc * 64 + fn * 16 + r16;
      const float bb = bias[col];
#pragma unroll
      for (int r = 0; r < 4; ++r) {
        const long row = m0 + wr * 64 + fm * 16 + g * 4 + r;
        const float v = acc[fm][fn][r] + bb;
        if (OUT_BF16) ((short*)C)[row * (long)N + col] = f2bf(v);
        else          ((float*)C)[row * (long)N + col] = v;
      }
    }
}

// ---------------------------------------------------------------------------
// Attention: one block per (b,h), 512 threads (8 waves) sharing ONE staged
// K/V LDS copy. QKV (25216 x 2304) bf16: cols [0,768)=Q, [768,1536)=K,
// [1536,2304)=V, head-major (h*64+d). Writes O in place over the Q columns
// (each wave reads its own Q rows -- hoisted to kernel entry -- before any
// wave writes them; rows are wave-private).
// K staged via global_load_lds into linear [208][64] with XOR chunk swizzle;
// V staged transposed [d][key]. PV P-bounce double-buffered (DS in-order).
// T5: setprio(1) around MFMA clusters (attn blocks are phase-independent).
// LDS: K 26624 + V 29696 + P 16384 = 72704 B -> 2 blocks/CU = 16 waves/CU.
__global__ __launch_bounds__(512, 4) void attn_kernel(short* QKV) {
  const int b = blockIdx.x / 12;
  const int h = blockIdx.x % 12;
  __shared__ short Ksm[208 * 64];      // linear, XOR-swizzled columns
  __shared__ short Vsm[64 * 232];      // V transposed [d][key], stride 232
  __shared__ short Psm[8][2][512];     // per-wave double-buffered 16x32 P tile
  const int tid = threadIdx.x;
  const long base = (long)b * 197 * 2304;
  const int lane = tid & 63, w = tid >> 6;  // w = 0..7
  const int r16 = lane & 15, g = lane >> 4;

  // hoist Q fragments for both q-tiles (qt = w and w+8)
  int qra = w * 16 + r16;            // qt = w (always < 13)
  const s16x8 qa0 = *(const s16x8*)(QKV + base + (long)qra * 2304 + h * 64 + g * 8);
  const s16x8 qa1 = *(const s16x8*)(QKV + base + (long)qra * 2304 + h * 64 + 32 + g * 8);
  s16x8 qb0 = {}, qb1 = {};
  if (w < 5) {                       // qt = w+8 exists (w+8 < 13)
    int qrb = (w + 8) * 16 + r16;
    if (qrb > 196) qrb = 196;        // clamp; computed but never stored
    qb0 = *(const s16x8*)(QKV + base + (long)qrb * 2304 + h * 64 + g * 8);
    qb1 = *(const s16x8*)(QKV + base + (long)qrb * 2304 + h * 64 + 32 + g * 8);
  }

  // stage K via async global_load_lds: 197 rows x 8 chunks, linear LDS dest,
  // pre-swizzled global source (rule #21)
  for (int c = tid; c < 1576; c += 512) {
    const int row = c >> 3;
    const int lc = (c & 7) ^ (row & 7);
    gload_lds16(QKV + base + (long)row * 2304 + 768 + h * 64 + lc * 8,
                Ksm + (c & ~63) * 8 /* wave-uniform base */ + (c & 63) * 8);
  }
  for (int c = tid; c < 88; c += 512)  // zero rows 197..207 (88 chunks)
    *(s16x8*)(Ksm + 197 * 64 + c * 8) = s16x8{};

  for (int c = tid; c < 224 * 8; c += 512) {  // stage V transposed (zero pad)
    const int key = c % 224, dch = c / 224;
    s16x8 val = {};
    if (key < 197)
      val = *(const s16x8*)(QKV + base + (long)key * 2304 + 1536 + h * 64 + dch * 8);
#pragma unroll
    for (int j = 0; j < 8; ++j) Vsm[(dch * 8 + j) * 232 + key] = val[j];
  }
  asm volatile("s_waitcnt vmcnt(0)" ::: "memory");
  __syncthreads();

  char* psw = (char*)Psm[w];

  for (int qt = w; qt < 13; qt += 8) {  // 13 q-tiles of 16 rows, 1-2 per wave
    const int q0 = qt * 16;
    const s16x8 qf0 = (qt == w) ? qa0 : qb0;
    const s16x8 qf1 = (qt == w) ? qa1 : qb1;

    f32x4 s[13];
#pragma unroll
    for (int kt = 0; kt < 13; ++kt) s[kt] = f32x4{0.f, 0.f, 0.f, 0.f};
    __builtin_amdgcn_s_setprio(1);
#pragma unroll
    for (int kt = 0; kt < 13; ++kt) {
      const int krow = kt * 16 + r16;
      const int sw = krow & 7;
      const s16x8 kf0 = *(const s16x8*)(Ksm + krow * 64 + ((g ^ sw) << 3));
      const s16x8 kf1 = *(const s16x8*)(Ksm + krow * 64 + (((g + 4) ^ sw) << 3));
      s[kt] = mfma16(qf0, kf0, s[kt]);
      s[kt] = mfma16(qf1, kf1, s[kt]);
    }
    __builtin_amdgcn_s_setprio(0);
    // scale, mask pad keys, row max (rows at (lane>>4)*4+reg, key=lane&15)
    float mr[4] = {-1e30f, -1e30f, -1e30f, -1e30f};
#pragma unroll
    for (int kt = 0; kt < 13; ++kt)
#pragma unroll
      for (int r = 0; r < 4; ++r) {
        float sv = s[kt][r] * 0.125f;
        if (kt == 12 && r16 >= 5) sv = -1e30f;  // keys 197..207
        s[kt][r] = sv;
        mr[r] = fmaxf(mr[r], sv);
      }
#pragma unroll
    for (int r = 0; r < 4; ++r) {
      mr[r] = fmaxf(mr[r], __shfl_xor(mr[r], 1, 64));
      mr[r] = fmaxf(mr[r], __shfl_xor(mr[r], 2, 64));
      mr[r] = fmaxf(mr[r], __shfl_xor(mr[r], 4, 64));
      mr[r] = fmaxf(mr[r], __shfl_xor(mr[r], 8, 64));
    }
    float sum[4] = {0.f, 0.f, 0.f, 0.f};
#pragma unroll
    for (int kt = 0; kt < 13; ++kt)
#pragma unroll
      for (int r = 0; r < 4; ++r) {
        const float p = __expf(s[kt][r] - mr[r]);
        s[kt][r] = p;
        sum[r] += p;
      }
#pragma unroll
    for (int r = 0; r < 4; ++r) {
      sum[r] += __shfl_xor(sum[r], 1, 64);
      sum[r] += __shfl_xor(sum[r], 2, 64);
      sum[r] += __shfl_xor(sum[r], 4, 64);
      sum[r] += __shfl_xor(sum[r], 8, 64);
    }
    // PV with double-buffered P bounce.
    f32x4 o[4];
#pragma unroll
    for (int df = 0; df < 4; ++df) o[df] = f32x4{0.f, 0.f, 0.f, 0.f};
    // prologue: write P(kb=0) -> buf 0
#pragma unroll
    for (int r = 0; r < 4; ++r) {
      const int prow = g * 4 + r;
      const int sw = (prow & 7) << 4;
      *(short*)(psw + ((prow * 64 + r16 * 2) ^ sw)) = f2bf(s[0][r]);
      *(short*)(psw + ((prow * 64 + (r16 + 16) * 2) ^ sw)) = f2bf(s[1][r]);
    }
    __builtin_amdgcn_s_setprio(1);
#pragma unroll
    for (int kb = 0; kb < 7; ++kb) {  // 7 blocks of 32 keys (last half-padded)
      char* bufr = psw + ((kb & 1) << 10);
      char* bufw = psw + (((kb & 1) ^ 1) << 10);
      // read P(kb) -- in-order DS guarantees the buf was written
      const s16x8 pa =
          *(const s16x8*)(bufr + ((r16 * 64 + g * 16) ^ ((r16 & 7) << 4)));
      if (kb < 6) {  // write P(kb+1) into the other buffer (overlaps MFMA)
#pragma unroll
        for (int r = 0; r < 4; ++r) {
          const int prow = g * 4 + r;
          const int sw = (prow & 7) << 4;
          const float p0f = s[2 * kb + 2][r];
          const float p1f = (kb < 5) ? s[2 * kb + 3][r] : 0.f;
          *(short*)(bufw + ((prow * 64 + r16 * 2) ^ sw)) = f2bf(p0f);
          *(short*)(bufw + ((prow * 64 + (r16 + 16) * 2) ^ sw)) = f2bf(p1f);
        }
      }
#pragma unroll
      for (int df = 0; df < 4; ++df) {
        const s16x8 vf = *(const s16x8*)(Vsm + (df * 16 + r16) * 232 + kb * 32 + g * 8);
        o[df] = mfma16(pa, vf, o[df]);
      }
    }
    __builtin_amdgcn_s_setprio(0);
    float rinv[4];
#pragma unroll
    for (int r = 0; r < 4; ++r) rinv[r] = 1.f / sum[r];
#pragma unroll
    for (int df = 0; df < 4; ++df)
#pragma unroll
      for (int r = 0; r < 4; ++r) {
        const int qrow = q0 + g * 4 + r;
        if (qrow < 197)
          QKV[base + (long)qrow * 2304 + h * 64 + df * 16 + r16] =
              f2bf(o[df][r] * rinv[r]);
      }
  }
}

// ---------------------------------------------------------------------------
extern "C" void kernel_launch(void* const* d_in, const int* in_sizes, int n_in,
                              void* d_out, int out_size, void* d_ws, size_t ws_size,
                              hipStream_t stream) {
  (void)in_sizes; (void)n_in; (void)out_size; (void)ws_size;
  const float* x   = (const float*)d_in[0];
  const float* Wq  = (const float*)d_in[1];
  const float* bq  = (const float*)d_in[2];
  const float* Wk  = (const float*)d_in[3];
  const float* bk  = (const float*)d_in[4];
  const float* Wv  = (const float*)d_in[5];
  const float* bv  = (const float*)d_in[6];
  const float* Wp  = (const float*)d_in[7];
  const float* bp  = (const float*)d_in[8];
  const float* lq1 = (const float*)d_in[9];
  const float* lk1 = (const float*)d_in[10];
  const float* lq2 = (const float*)d_in[11];
  const float* lk2 = (const float*)d_in[12];
  const float* lambda_init = (const float*)d_in[14];

  // workspace layout (bytes, 256-aligned); total 159,655,168
  char* ws = (char*)d_ws;
  short* xb   = (short*)ws;                  // x bf16: 25216x768
  short* wqkv = (short*)(ws + 38731776);     // [Wq;Wk;Wv] bf16: 2304x768
  short* wpb  = (short*)(ws + 42270720);     // Wp' bf16: 768x768
  float* bqkv = (float*)(ws + 43450368);     // [bq;bk;bv] f32: 2304
  float* lvp  = (float*)(ws + 43459584);     // lv scalar
  short* qkv  = (short*)(ws + 43459840);     // QKV bf16: 25216x2304 (O aliases Q cols)

  prep_kernel<<<2914, 256, 0, stream>>>(x, Wq, Wk, Wv, bq, bk, bv,
                                        lq1, lk1, lq2, lk2, lambda_init,
                                        xb, wqkv, bqkv, lvp);
  cvt_wp_prime<<<288, 256, 0, stream>>>(Wp, lvp, wpb);  // after prep (lv dep)

  // GEMM1: QKV = xb(25216x768) @ wqkv^T(2304x768), K=12*64
  gemm_bt<1, 12><<<197 * 18, 256, 0, stream>>>(xb, 768, wqkv, bqkv, qkv,
                                               25216, 2304);
  attn_kernel<<<128 * 12, 512, 0, stream>>>(qkv);
  // GEMM2: out = attnO(25216x768, lda=2304) @ Wp'^T(768x768) + bp, K=12*64
  gemm_bt<0, 12><<<197 * 6, 256, 0, stream>>>(qkv, 2304, wpb, bp, d_out,
                                              25216, 768);
}